// Round 14
// baseline (3302.191 us; speedup 1.0000x reference)
//
#include <hip/hip_runtime.h>
#include <math.h>

#define N_NODES 200000
#define N_EDGES 800000
#define N_GRAPHS 8192
#define B1 16       // dst nodes per block, layer-1 fused
#define B2G 16      // dst nodes per block, layer-2 gather
#define EC2 128

typedef unsigned short ushort_t;

__device__ __forceinline__ float selu_f(float x){
  const float alpha = 1.6732632423543772f;
  const float lam   = 1.0507009873554805f;
  return x > 0.f ? lam * x : lam * alpha * (expf(x) - 1.f);
}
__device__ __forceinline__ float dot4(float4 a, float4 b){
  return a.x * b.x + a.y * b.y + a.z * b.z + a.w * b.w;
}

// ---------------- utility ----------------
__global__ void zero_i32(int* p, int n){
  int i = blockIdx.x * 256 + threadIdx.x;
  if (i < n) p[i] = 0;
}

// ---------------- CSR build ----------------
__global__ void deg_kernel(const int* __restrict__ dst, int* __restrict__ deg, int E){
  int e = blockIdx.x * 256 + threadIdx.x;
  if (e < E) atomicAdd(&deg[dst[e]], 1);
}

__global__ void scan1(const int* __restrict__ deg, int* __restrict__ rp, int* __restrict__ bs, int n){
  __shared__ int sh[256];
  int t = threadIdx.x;
  int base = blockIdx.x * 1024;
  int v[4]; int s = 0;
  #pragma unroll
  for (int i = 0; i < 4; i++){
    int idx = base + t * 4 + i;
    v[i] = (idx < n) ? deg[idx] : 0;
    s += v[i];
  }
  sh[t] = s; __syncthreads();
  for (int off = 1; off < 256; off <<= 1){
    int x = (t >= off) ? sh[t - off] : 0;
    __syncthreads();
    sh[t] += x;
    __syncthreads();
  }
  int run = (t == 0) ? 0 : sh[t - 1];
  #pragma unroll
  for (int i = 0; i < 4; i++){
    int idx = base + t * 4 + i;
    if (idx < n) rp[idx] = run;
    run += v[i];
  }
  if (t == 255) bs[blockIdx.x] = sh[255];
}

__global__ void scan2(int* bs, int nb){
  __shared__ int sh[256];
  int t = threadIdx.x;
  sh[t] = (t < nb) ? bs[t] : 0; __syncthreads();
  for (int off = 1; off < 256; off <<= 1){
    int x = (t >= off) ? sh[t - off] : 0;
    __syncthreads();
    sh[t] += x;
    __syncthreads();
  }
  int excl = (t == 0) ? 0 : sh[t - 1];
  if (t < nb) bs[t] = excl;
}

__global__ void scan3(int* rp, const int* __restrict__ bs, int n, int total){
  int i = blockIdx.x * 256 + threadIdx.x;
  if (i < n) rp[i] += bs[i >> 10];
  if (i == 0) rp[n] = total;
}

__global__ void fill_csr(const int* __restrict__ src, const int* __restrict__ dst,
                         const int* __restrict__ rp, int* __restrict__ fil,
                         int* __restrict__ csr, int E){
  int e = blockIdx.x * 256 + threadIdx.x;
  if (e < E){
    int d = dst[e];
    int p = atomicAdd(&fil[d], 1);
    csr[rp[d] + p] = src[e];
  }
}

// ---------------- V = attn^T W precompute ----------------
__global__ void compute_v(const float* __restrict__ W1, const float* __restrict__ al1, const float* __restrict__ ar1,
                          const float* __restrict__ W2, const float* __restrict__ al2, const float* __restrict__ ar2,
                          const float* __restrict__ W3, const float* __restrict__ al3, const float* __restrict__ ar3,
                          float* __restrict__ V1L, float* __restrict__ V1R,
                          float* __restrict__ V2L, float* __restrict__ V2R,
                          float* __restrict__ V3L, float* __restrict__ V3R){
  int i = blockIdx.x * 256 + threadIdx.x;
  if (i < 512){
    int h = i >> 7, k = i & 127;
    float sl = 0.f, sr = 0.f;
    for (int dd = 0; dd < 64; dd++){
      float w = W1[(size_t)(h * 64 + dd) * 128 + k];
      sl += al1[h * 64 + dd] * w;
      sr += ar1[h * 64 + dd] * w;
    }
    V1L[i] = sl; V1R[i] = sr;
  } else if (i < 1536){
    int j = i - 512;
    int h = j >> 8, k = j & 255;
    float sl = 0.f, sr = 0.f;
    for (int dd = 0; dd < 64; dd++){
      float w = W2[(size_t)(h * 64 + dd) * 256 + k];
      sl += al2[h * 64 + dd] * w;
      sr += ar2[h * 64 + dd] * w;
    }
    V2L[j] = sl; V2R[j] = sr;
  } else if (i < 1792){
    int k = i - 1536;
    float sl = 0.f, sr = 0.f;
    for (int dd = 0; dd < 64; dd++){
      float w = W3[(size_t)dd * 256 + k];
      sl += al3[dd] * w;
      sr += ar3[dd] * w;
    }
    V3L[k] = sl; V3R[k] = sr;
  }
}

// ---------------- el/er for layer 1 ----------------
__global__ __launch_bounds__(256) void el_er1(const float* __restrict__ x0,
                                              const float* __restrict__ V1L, const float* __restrict__ V1R,
                                              float* __restrict__ el1, float* __restrict__ er1, int n){
  __shared__ float vl[512], vr[512];
  int t = threadIdx.x;
  for (int i = t; i < 512; i += 256){ vl[i] = V1L[i]; vr[i] = V1R[i]; }
  __syncthreads();
  int node = blockIdx.x * 4 + (t >> 6);
  int l = t & 63;
  if (node >= n) return;
  float xa = x0[(size_t)node * 128 + l];
  float xb = x0[(size_t)node * 128 + 64 + l];
  #pragma unroll
  for (int h = 0; h < 4; h++){
    float pl = xa * vl[h * 128 + l] + xb * vl[h * 128 + 64 + l];
    float pr = xa * vr[h * 128 + l] + xb * vr[h * 128 + 64 + l];
    #pragma unroll
    for (int off = 32; off; off >>= 1){ pl += __shfl_xor(pl, off); pr += __shfl_xor(pr, off); }
    if (l == 0){ el1[(size_t)node * 4 + h] = pl; er1[(size_t)node * 4 + h] = pr; }
  }
}

// ---------------- alpha kernels ----------------
__global__ __launch_bounds__(256) void alpha_h4(const float* __restrict__ el, const float* __restrict__ er,
                                                const int* __restrict__ rp, const int* __restrict__ csr,
                                                float* __restrict__ a, int n){
  int node = blockIdx.x * 256 + threadIdx.x;
  if (node >= n) return;
  int s0 = rp[node], s1 = rp[node + 1];
  if (s0 >= s1) return;
  float4 erv = *reinterpret_cast<const float4*>(er + (size_t)node * 4);
  float m0 = -1e30f, m1 = -1e30f, m2 = -1e30f, m3 = -1e30f;
  for (int i = s0; i < s1; i++){
    float4 e = *reinterpret_cast<const float4*>(el + (size_t)csr[i] * 4);
    float e0 = e.x + erv.x; e0 = e0 > 0.f ? e0 : 0.2f * e0; m0 = fmaxf(m0, e0);
    float e1 = e.y + erv.y; e1 = e1 > 0.f ? e1 : 0.2f * e1; m1 = fmaxf(m1, e1);
    float e2 = e.z + erv.z; e2 = e2 > 0.f ? e2 : 0.2f * e2; m2 = fmaxf(m2, e2);
    float e3 = e.w + erv.w; e3 = e3 > 0.f ? e3 : 0.2f * e3; m3 = fmaxf(m3, e3);
  }
  float d0 = 0.f, d1 = 0.f, d2 = 0.f, d3 = 0.f;
  for (int i = s0; i < s1; i++){
    float4 e = *reinterpret_cast<const float4*>(el + (size_t)csr[i] * 4);
    float e0 = e.x + erv.x; e0 = e0 > 0.f ? e0 : 0.2f * e0; d0 += expf(e0 - m0);
    float e1 = e.y + erv.y; e1 = e1 > 0.f ? e1 : 0.2f * e1; d1 += expf(e1 - m1);
    float e2 = e.z + erv.z; e2 = e2 > 0.f ? e2 : 0.2f * e2; d2 += expf(e2 - m2);
    float e3 = e.w + erv.w; e3 = e3 > 0.f ? e3 : 0.2f * e3; d3 += expf(e3 - m3);
  }
  d0 = 1.f / d0; d1 = 1.f / d1; d2 = 1.f / d2; d3 = 1.f / d3;
  for (int i = s0; i < s1; i++){
    float4 e = *reinterpret_cast<const float4*>(el + (size_t)csr[i] * 4);
    float4 o;
    float e0 = e.x + erv.x; e0 = e0 > 0.f ? e0 : 0.2f * e0; o.x = expf(e0 - m0) * d0;
    float e1 = e.y + erv.y; e1 = e1 > 0.f ? e1 : 0.2f * e1; o.y = expf(e1 - m1) * d1;
    float e2 = e.z + erv.z; e2 = e2 > 0.f ? e2 : 0.2f * e2; o.z = expf(e2 - m2) * d2;
    float e3 = e.w + erv.w; e3 = e3 > 0.f ? e3 : 0.2f * e3; o.w = expf(e3 - m3) * d3;
    *reinterpret_cast<float4*>(a + (size_t)i * 4) = o;
  }
}

__global__ __launch_bounds__(256) void alpha_h1(const float* __restrict__ el, const float* __restrict__ er,
                                                const int* __restrict__ rp, const int* __restrict__ csr,
                                                float* __restrict__ a, int n){
  int node = blockIdx.x * 256 + threadIdx.x;
  if (node >= n) return;
  int s0 = rp[node], s1 = rp[node + 1];
  if (s0 >= s1) return;
  float erv = er[node];
  float m = -1e30f;
  for (int i = s0; i < s1; i++){
    float e = el[csr[i]] + erv; e = e > 0.f ? e : 0.2f * e; m = fmaxf(m, e);
  }
  float den = 0.f;
  for (int i = s0; i < s1; i++){
    float e = el[csr[i]] + erv; e = e > 0.f ? e : 0.2f * e; den += expf(e - m);
  }
  float inv = 1.f / den;
  for (int i = s0; i < s1; i++){
    float e = el[csr[i]] + erv; e = e > 0.f ? e : 0.2f * e; a[i] = expf(e - m) * inv;
  }
}

// ---- layer-1 part A: gather x0 -> GEMM1 -> x1 tile -> el2/er2 + x1 24-bit store ----
__global__ __launch_bounds__(512, 4) void l1a(
    const float* __restrict__ x0, const float* __restrict__ W1, const float* __restrict__ bias1,
    const float* __restrict__ a1,
    const float* __restrict__ V2L, const float* __restrict__ V2R,
    const int* __restrict__ rp, const int* __restrict__ csr,
    ushort_t* __restrict__ zhi, unsigned char* __restrict__ zlo,
    float* __restrict__ el2, float* __restrict__ er2){
  __shared__ float aggT[4][B1][132];    // [h][d][k]  33792 B
  __shared__ int rpc[B1 + 1];
  float* x1s = &aggT[0][0][0];          // overlay [16][260] after GEMM1
  int t = threadIdx.x;
  int nb0 = blockIdx.x * B1;
  if (t <= B1) rpc[t] = rp[nb0 + t];
  __syncthreads();

  // ---- gather: half-wave (32 lanes) per dst, float4 cols, depth-2 pipelined ----
  {
    int g = t >> 5, c4 = t & 31;
    int i0 = rpc[g], i1 = rpc[g + 1];
    float acc[4][4] = {{0.f}};
    int s = (i0 < i1) ? csr[i0] : 0;
    for (int i = i0; i < i1; i++){
      int sn = (i + 1 < i1) ? csr[i + 1] : 0;
      float4 av = *reinterpret_cast<const float4*>(a1 + (size_t)i * 4);
      float4 xv = *reinterpret_cast<const float4*>(x0 + (size_t)s * 128 + c4 * 4);
      acc[0][0] += av.x * xv.x; acc[0][1] += av.x * xv.y; acc[0][2] += av.x * xv.z; acc[0][3] += av.x * xv.w;
      acc[1][0] += av.y * xv.x; acc[1][1] += av.y * xv.y; acc[1][2] += av.y * xv.z; acc[1][3] += av.y * xv.w;
      acc[2][0] += av.z * xv.x; acc[2][1] += av.z * xv.y; acc[2][2] += av.z * xv.z; acc[2][3] += av.z * xv.w;
      acc[3][0] += av.w * xv.x; acc[3][1] += av.w * xv.y; acc[3][2] += av.w * xv.z; acc[3][3] += av.w * xv.w;
      s = sn;
    }
    #pragma unroll
    for (int h = 0; h < 4; h++){
      float4 v = make_float4(acc[h][0], acc[h][1], acc[h][2], acc[h][3]);
      *reinterpret_cast<float4*>(&aggT[h][g][c4 * 4]) = v;
    }
  }
  __syncthreads();

  // ---- GEMM1: mq = t>>3 (0..63), dg = t&7; 4m x 2d per thread ----
  int mq = t >> 3, dg = t & 7;
  int m0 = mq * 4;
  int hh = mq >> 4;
  float acc1[4][2];
  {
    #pragma unroll
    for (int j = 0; j < 4; j++){ acc1[j][0] = 0.f; acc1[j][1] = 0.f; }
    const float* wp = W1 + (size_t)m0 * 128;
    #pragma unroll 2
    for (int kq = 0; kq < 32; kq++){
      int k = kq * 4;
      float4 w0 = *reinterpret_cast<const float4*>(wp + k);
      float4 w1 = *reinterpret_cast<const float4*>(wp + 128 + k);
      float4 w2 = *reinterpret_cast<const float4*>(wp + 256 + k);
      float4 w3 = *reinterpret_cast<const float4*>(wp + 384 + k);
      float4 a0 = *reinterpret_cast<const float4*>(&aggT[hh][dg][k]);
      float4 a1v = *reinterpret_cast<const float4*>(&aggT[hh][dg + 8][k]);
      acc1[0][0] += dot4(w0, a0); acc1[0][1] += dot4(w0, a1v);
      acc1[1][0] += dot4(w1, a0); acc1[1][1] += dot4(w1, a1v);
      acc1[2][0] += dot4(w2, a0); acc1[2][1] += dot4(w2, a1v);
      acc1[3][0] += dot4(w3, a0); acc1[3][1] += dot4(w3, a1v);
    }
  }
  __syncthreads();                      // aggT reads done -> overlay x1s
  {
    float4 b = *reinterpret_cast<const float4*>(bias1 + m0);
    #pragma unroll
    for (int r = 0; r < 2; r++){
      int d = dg + 8 * r;
      float4 v;
      v.x = selu_f(acc1[0][r] + b.x);
      v.y = selu_f(acc1[1][r] + b.y);
      v.z = selu_f(acc1[2][r] + b.z);
      v.w = selu_f(acc1[3][r] + b.w);
      *reinterpret_cast<float4*>(&x1s[d * 260 + m0]) = v;
    }
  }
  __syncthreads();

  // ---- coalesced 24-bit split store of x1 ----
  {
    int row = t >> 5, cq = t & 31;
    #pragma unroll
    for (int it = 0; it < 2; it++){
      int c4 = cq + it * 32;
      float4 v = *reinterpret_cast<float4*>(&x1s[row * 260 + c4 * 4]);
      unsigned int ux = __float_as_uint(v.x) + 0x80u, uy = __float_as_uint(v.y) + 0x80u;
      unsigned int uz = __float_as_uint(v.z) + 0x80u, uw = __float_as_uint(v.w) + 0x80u;
      ushort4 h4; uchar4 l4;
      h4.x = (ushort_t)(ux >> 16); h4.y = (ushort_t)(uy >> 16);
      h4.z = (ushort_t)(uz >> 16); h4.w = (ushort_t)(uw >> 16);
      l4.x = (unsigned char)(ux >> 8); l4.y = (unsigned char)(uy >> 8);
      l4.z = (unsigned char)(uz >> 8); l4.w = (unsigned char)(uw >> 8);
      size_t base = (size_t)(nb0 + row) * 256 + c4 * 4;
      *reinterpret_cast<ushort4*>(zhi + base) = h4;
      *reinterpret_cast<uchar4*>(zlo + base) = l4;
    }
  }

  // ---- el2/er2 from fp32 x1 tile ----
  if (t < 128){
    int d = t & 15, hq = (t >> 4) & 3, lr = t >> 6;
    const float* V = lr ? V2R : V2L;
    const float4* Vq = reinterpret_cast<const float4*>(V + hq * 256);
    const float4* Xq = reinterpret_cast<const float4*>(&x1s[d * 260]);
    float p = 0.f;
    #pragma unroll 4
    for (int q = 0; q < 64; q++){
      float4 v = Vq[q]; float4 x = Xq[q];
      p += v.x * x.x; p += v.y * x.y; p += v.z * x.z; p += v.w * x.w;
    }
    if (lr) er2[(size_t)(nb0 + d) * 4 + hq] = p;
    else    el2[(size_t)(nb0 + d) * 4 + hq] = p;
  }
}

// ---- layer-1 part B: in-place per-node transform z: x1 -> y1 = W2*x1 (24-bit rounded) ----
__global__ __launch_bounds__(512, 4) void y_transform(
    ushort_t* __restrict__ zhi, unsigned char* __restrict__ zlo,
    const float* __restrict__ W2){
  __shared__ float x1s[32 * 260];       // 33280 B
  int t = threadIdx.x;
  int nb0 = blockIdx.x * 32;
  // unpack 32 rows of x1 to fp32 LDS
  for (int i = t; i < 32 * 64; i += 512){
    int d = i >> 6, c4 = i & 63;
    size_t base = (size_t)(nb0 + d) * 256 + c4 * 4;
    ushort4 hv = *reinterpret_cast<const ushort4*>(zhi + base);
    uchar4  lv = *reinterpret_cast<const uchar4*>(zlo + base);
    float4 v;
    v.x = __uint_as_float(((unsigned int)hv.x << 16) | ((unsigned int)lv.x << 8));
    v.y = __uint_as_float(((unsigned int)hv.y << 16) | ((unsigned int)lv.y << 8));
    v.z = __uint_as_float(((unsigned int)hv.z << 16) | ((unsigned int)lv.z << 8));
    v.w = __uint_as_float(((unsigned int)hv.w << 16) | ((unsigned int)lv.w << 8));
    *reinterpret_cast<float4*>(&x1s[d * 260 + c4 * 4]) = v;
  }
  __syncthreads();
  // GEMM: thread = (mq = t&63, dgrp = t>>6); outputs m0..m0+3 x d = dgrp*4..+3
  int mq = t & 63, dgrp = t >> 6;       // dgrp uniform per wave
  int m0 = mq * 4;
  float acc[4][4];
  #pragma unroll
  for (int j = 0; j < 4; j++)
    #pragma unroll
    for (int r = 0; r < 4; r++) acc[j][r] = 0.f;
  const float* wp = W2 + (size_t)m0 * 256;
  #pragma unroll 2
  for (int kq = 0; kq < 64; kq++){
    int k = kq * 4;
    float4 w0 = *reinterpret_cast<const float4*>(wp + k);
    float4 w1 = *reinterpret_cast<const float4*>(wp + 256 + k);
    float4 w2 = *reinterpret_cast<const float4*>(wp + 512 + k);
    float4 w3 = *reinterpret_cast<const float4*>(wp + 768 + k);
    #pragma unroll
    for (int r = 0; r < 4; r++){
      float4 xv = *reinterpret_cast<const float4*>(&x1s[(dgrp * 4 + r) * 260 + k]);
      acc[0][r] += dot4(w0, xv);
      acc[1][r] += dot4(w1, xv);
      acc[2][r] += dot4(w2, xv);
      acc[3][r] += dot4(w3, xv);
    }
  }
  // write y1 back in place (24-bit rounded); rows owned exclusively by this block
  #pragma unroll
  for (int r = 0; r < 4; r++){
    int d = dgrp * 4 + r;
    unsigned int u0 = __float_as_uint(acc[0][r]) + 0x80u;
    unsigned int u1 = __float_as_uint(acc[1][r]) + 0x80u;
    unsigned int u2 = __float_as_uint(acc[2][r]) + 0x80u;
    unsigned int u3 = __float_as_uint(acc[3][r]) + 0x80u;
    ushort4 h4; uchar4 l4;
    h4.x = (ushort_t)(u0 >> 16); h4.y = (ushort_t)(u1 >> 16);
    h4.z = (ushort_t)(u2 >> 16); h4.w = (ushort_t)(u3 >> 16);
    l4.x = (unsigned char)(u0 >> 8); l4.y = (unsigned char)(u1 >> 8);
    l4.z = (unsigned char)(u2 >> 8); l4.w = (unsigned char)(u3 >> 8);
    size_t base = (size_t)(nb0 + d) * 256 + m0;
    *reinterpret_cast<ushort4*>(zhi + base) = h4;
    *reinterpret_cast<uchar4*>(zlo + base) = l4;
  }
}

// ---- layer-2 gather: x2 = selu(sum a2*y1 + b2) -> el3/er3 + feat3 = W3*x2 ----
__global__ __launch_bounds__(256, 4) void l2_gather(
    const ushort_t* __restrict__ y1hi, const unsigned char* __restrict__ y1lo,
    const float* __restrict__ bias2, const float* __restrict__ a2,
    const float* __restrict__ W3,
    const float* __restrict__ V3L, const float* __restrict__ V3R,
    const int* __restrict__ rp, const int* __restrict__ csr,
    float* __restrict__ feat3, float* __restrict__ el3, float* __restrict__ er3){
  __shared__ float x2s[B2G][257];       // 16448 B
  __shared__ float W3c[16 * 257];       // 16448 B
  __shared__ float als[EC2][4];
  __shared__ int   ssrc[EC2];
  __shared__ int   rpc[B2G + 1];
  int t = threadIdx.x;
  int nb0 = blockIdx.x * B2G;
  if (t <= B2G) rpc[t] = rp[nb0 + t];
  __syncthreads();
  int e0 = rpc[0], eN = rpc[B2G];
  int c = t;                            // column 0..255
  int h = c >> 6;

  float acc[B2G];
  #pragma unroll
  for (int d = 0; d < B2G; d++) acc[d] = 0.f;

  for (int c0 = e0; c0 < eN; c0 += EC2){
    int ce = min(EC2, eN - c0);
    for (int i = t; i < ce; i += 256){
      ssrc[i] = csr[c0 + i];
      float4 av = *reinterpret_cast<const float4*>(a2 + (size_t)(c0 + i) * 4);
      als[i][0] = av.x; als[i][1] = av.y; als[i][2] = av.z; als[i][3] = av.w;
    }
    __syncthreads();
    #pragma unroll
    for (int d = 0; d < B2G; d++){
      int lo = max(rpc[d], c0) - c0;
      int hi = min(rpc[d + 1], c0 + ce) - c0;
      for (int i = lo; i < hi; i++){
        size_t s = (size_t)ssrc[i] * 256 + c;
        unsigned int u = ((unsigned int)y1hi[s] << 16) | ((unsigned int)y1lo[s] << 8);
        acc[d] += als[i][h] * __uint_as_float(u);
      }
    }
    __syncthreads();
  }
  {
    float b = bias2[c];
    #pragma unroll
    for (int d = 0; d < B2G; d++) x2s[d][c] = selu_f(acc[d] + b);
  }
  __syncthreads();

  // el3/er3: 32 tasks x 8 threads, interleaved k
  {
    int task = t >> 3, j = t & 7;
    int d = task & 15, lr = task >> 4;
    const float* V = lr ? V3R : V3L;
    float p = 0.f;
    for (int kk = 0; kk < 32; kk++){
      int k = j + kk * 8;
      p += V[k] * x2s[d][k];
    }
    p += __shfl_xor(p, 1); p += __shfl_xor(p, 2); p += __shfl_xor(p, 4);
    if (j == 0){ if (lr) er3[nb0 + d] = p; else el3[nb0 + d] = p; }
  }

  // feat3 = W3 . x2 : 4 chunks of 16 rows staged in LDS
  for (int ch = 0; ch < 4; ch++){
    __syncthreads();
    for (int i = t; i < 16 * 64; i += 256){
      int r = i >> 6, k4 = i & 63;
      float4 w = *reinterpret_cast<const float4*>(W3 + (size_t)(ch * 16 + r) * 256 + k4 * 4);
      W3c[r * 257 + k4 * 4 + 0] = w.x; W3c[r * 257 + k4 * 4 + 1] = w.y;
      W3c[r * 257 + k4 * 4 + 2] = w.z; W3c[r * 257 + k4 * 4 + 3] = w.w;
    }
    __syncthreads();
    {
      int r = t & 15, d = t >> 4;
      float s = 0.f;
      #pragma unroll 4
      for (int k = 0; k < 256; k++) s += W3c[r * 257 + k] * x2s[d][k];
      feat3[(size_t)(nb0 + d) * 64 + ch * 16 + r] = s;
    }
  }
}

// ---------------- layer-3 aggregation, 4-edge batched ----------------
__global__ __launch_bounds__(256) void gat_agg3(const float* __restrict__ feat, const float* __restrict__ a3,
                                                const int* __restrict__ rp, const int* __restrict__ csr,
                                                const float* __restrict__ bias,
                                                float* __restrict__ out, int n){
  int node = blockIdx.x * 4 + (threadIdx.x >> 6);
  int t = threadIdx.x & 63;
  if (node >= n) return;
  int s0 = rp[node], s1 = rp[node + 1];
  float acc = 0.f;
  for (int i = s0; i < s1; i += 4){
    float a[4], f[4];
    #pragma unroll
    for (int j = 0; j < 4; j++){
      int idx = i + j;
      bool vld = idx < s1;
      int idc = vld ? idx : s1 - 1;
      float av = a3[idc];
      if (!vld) av = 0.f;
      a[j] = av;
      f[j] = feat[(size_t)csr[idc] * 64 + t];
    }
    acc += a[0] * f[0] + a[1] * f[1] + a[2] * f[2] + a[3] * f[3];
  }
  out[(size_t)node * 64 + t] = selu_f(acc + bias[t]);
}

// ---------------- readout ----------------
__global__ void readout_kernel(const float* __restrict__ x3, const float* __restrict__ score_w,
                               const float* __restrict__ score_b, const int* __restrict__ gids,
                               float* __restrict__ num, float* __restrict__ den, int n){
  int node = blockIdx.x * 4 + (threadIdx.x >> 6);
  int lane = threadIdx.x & 63;
  if (node >= n) return;
  float xv = x3[(size_t)node * 64 + lane];
  float p = xv * score_w[lane];
  #pragma unroll
  for (int off = 32; off; off >>= 1) p += __shfl_xor(p, off);
  float w = 1.f / (1.f + expf(-(p + score_b[0])));
  int g = gids[node];
  atomicAdd(&num[(size_t)g * 64 + lane], w * xv);
  if (lane == 0) atomicAdd(&den[g], w);
}

// ---------------- final MLP ----------------
__global__ __launch_bounds__(128) void mlp_kernel(
    const float* __restrict__ num, const float* __restrict__ den,
    const float* __restrict__ fg,
    const float* __restrict__ w1, const float* __restrict__ b1,
    const float* __restrict__ w2, const float* __restrict__ b2,
    const float* __restrict__ w3, const float* __restrict__ b3,
    float* __restrict__ out, int G){
  __shared__ float z[80];
  __shared__ float h1[128];
  __shared__ float h2[64];
  int t = threadIdx.x;
  for (int g = blockIdx.x; g < G; g += gridDim.x){
    if (t < 64){
      float d = den[g];
      d = (d == 0.f) ? 1.f : d;
      z[t] = num[(size_t)g * 64 + t] / d;
    } else if (t < 80){
      z[t] = fg[(size_t)g * 16 + (t - 64)];
    }
    __syncthreads();
    {
      float a = b1[t];
      for (int k = 0; k < 80; k++) a += z[k] * w1[t * 80 + k];
      h1[t] = selu_f(a);
    }
    __syncthreads();
    if (t < 64){
      float a = b2[t];
      for (int k = 0; k < 128; k++) a += h1[k] * w2[t * 128 + k];
      h2[t] = selu_f(a);
    }
    __syncthreads();
    if (t < 64){
      float p = h2[t] * w3[t];
      #pragma unroll
      for (int off = 32; off; off >>= 1) p += __shfl_down(p, off);
      if (t == 0) out[g] = p + b3[0];
    }
    __syncthreads();
  }
}

// ---------------- launch ----------------
extern "C" void kernel_launch(void* const* d_in, const int* in_sizes, int n_in,
                              void* d_out, int out_size, void* d_ws, size_t ws_size,
                              hipStream_t stream) {
  const float* feats_node  = (const float*)d_in[0];
  const float* feats_graph = (const float*)d_in[1];
  const int*   src         = (const int*)d_in[2];
  const int*   dst         = (const int*)d_in[3];
  const int*   gids        = (const int*)d_in[4];
  const float* fc1_w   = (const float*)d_in[5];
  const float* attn_l1 = (const float*)d_in[6];
  const float* attn_r1 = (const float*)d_in[7];
  const float* bias1   = (const float*)d_in[8];
  const float* fc2_w   = (const float*)d_in[9];
  const float* attn_l2 = (const float*)d_in[10];
  const float* attn_r2 = (const float*)d_in[11];
  const float* bias2   = (const float*)d_in[12];
  const float* fc3_w   = (const float*)d_in[13];
  const float* attn_l3 = (const float*)d_in[14];
  const float* attn_r3 = (const float*)d_in[15];
  const float* bias3   = (const float*)d_in[16];
  const float* score_w = (const float*)d_in[17];
  const float* score_b = (const float*)d_in[18];
  const float* mlp_w1  = (const float*)d_in[19];
  const float* mlp_b1  = (const float*)d_in[20];
  const float* mlp_w2  = (const float*)d_in[21];
  const float* mlp_b2  = (const float*)d_in[22];
  const float* mlp_w3  = (const float*)d_in[23];
  const float* mlp_b3  = (const float*)d_in[24];
  float* out = (float*)d_out;

  char* ws = (char*)d_ws;
  size_t off = 0;
  auto alloc = [&](size_t bytes) -> void* {
    void* p = ws + off;
    off += (bytes + 255) / 256 * 256;
    return p;
  };
  int*   deg   = (int*)alloc((size_t)N_NODES * 4);
  int*   fil   = (int*)alloc((size_t)N_NODES * 4);
  int*   rp    = (int*)alloc((size_t)(N_NODES + 1) * 4);
  int*   bs    = (int*)alloc(256 * 4);
  int*   csr   = (int*)alloc((size_t)N_EDGES * 4);
  float* elbuf = (float*)alloc((size_t)N_NODES * 4 * 4);
  float* erbuf = (float*)alloc((size_t)N_NODES * 4 * 4);
  float* V1L   = (float*)alloc(512 * 4);
  float* V1R   = (float*)alloc(512 * 4);
  float* V2L   = (float*)alloc(1024 * 4);
  float* V2R   = (float*)alloc(1024 * 4);
  float* V3L   = (float*)alloc(256 * 4);
  float* V3R   = (float*)alloc(256 * 4);
  float* num   = (float*)alloc((size_t)N_GRAPHS * 64 * 4);
  float* den   = (float*)alloc((size_t)N_GRAPHS * 4);
  float* A     = (float*)alloc((size_t)N_EDGES * 4 * 4);
  float* feat3 = (float*)alloc((size_t)N_NODES * 64 * 4);
  ushort_t*      zhi = (ushort_t*)alloc((size_t)N_NODES * 256 * 2);
  unsigned char* zlo = (unsigned char*)alloc((size_t)N_NODES * 256);
  float* x3 = (float*)zhi;  // overlay: z dead after l2_gather

  zero_i32<<<(N_NODES + 255) / 256, 256, 0, stream>>>(deg, N_NODES);
  zero_i32<<<(N_NODES + 255) / 256, 256, 0, stream>>>(fil, N_NODES);
  zero_i32<<<(N_GRAPHS * 64 + 255) / 256, 256, 0, stream>>>((int*)num, N_GRAPHS * 64);
  zero_i32<<<(N_GRAPHS + 255) / 256, 256, 0, stream>>>((int*)den, N_GRAPHS);

  deg_kernel<<<(N_EDGES + 255) / 256, 256, 0, stream>>>(dst, deg, N_EDGES);
  scan1<<<196, 256, 0, stream>>>(deg, rp, bs, N_NODES);
  scan2<<<1, 256, 0, stream>>>(bs, 196);
  scan3<<<(N_NODES + 255) / 256, 256, 0, stream>>>(rp, bs, N_NODES, N_EDGES);
  fill_csr<<<(N_EDGES + 255) / 256, 256, 0, stream>>>(src, dst, rp, fil, csr, N_EDGES);

  compute_v<<<7, 256, 0, stream>>>(fc1_w, attn_l1, attn_r1, fc2_w, attn_l2, attn_r2,
                                   fc3_w, attn_l3, attn_r3, V1L, V1R, V2L, V2R, V3L, V3R);
  el_er1<<<N_NODES / 4, 256, 0, stream>>>(feats_node, V1L, V1R, elbuf, erbuf, N_NODES);

  // layer 1: gather+GEMM1+el2, then in-place y1 = W2*x1 transform
  alpha_h4<<<(N_NODES + 255) / 256, 256, 0, stream>>>(elbuf, erbuf, rp, csr, A, N_NODES);
  l1a<<<N_NODES / B1, 512, 0, stream>>>(feats_node, fc1_w, bias1, A,
                                        V2L, V2R, rp, csr, zhi, zlo, elbuf, erbuf);
  y_transform<<<N_NODES / 32, 512, 0, stream>>>(zhi, zlo, fc2_w);

  // layer 2 (pure gather of y1)
  alpha_h4<<<(N_NODES + 255) / 256, 256, 0, stream>>>(elbuf, erbuf, rp, csr, A, N_NODES);
  l2_gather<<<N_NODES / B2G, 256, 0, stream>>>(zhi, zlo, bias2, A, fc3_w,
                                               V3L, V3R, rp, csr, feat3, elbuf, erbuf);
  // layer 3
  alpha_h1<<<(N_NODES + 255) / 256, 256, 0, stream>>>(elbuf, erbuf, rp, csr, A, N_NODES);
  gat_agg3<<<N_NODES / 4, 256, 0, stream>>>(feat3, A, rp, csr, bias3, x3, N_NODES);

  readout_kernel<<<N_NODES / 4, 256, 0, stream>>>(x3, score_w, score_b, gids, num, den, N_NODES);
  mlp_kernel<<<256, 128, 0, stream>>>(num, den, feats_graph,
                                      mlp_w1, mlp_b1, mlp_w2, mlp_b2, mlp_w3, mlp_b3,
                                      out, N_GRAPHS);
}

// Round 15
// 2404.694 us; speedup vs baseline: 1.3732x; 1.3732x over previous
//
#include <hip/hip_runtime.h>
#include <math.h>

#define N_NODES 200000
#define N_EDGES 800000
#define N_GRAPHS 8192
#define B1 16       // dst nodes per block, layer-1 fused
#define B2G 16      // dst nodes per block, layer-2 gather
#define EC2 128

typedef unsigned short ushort_t;

__device__ __forceinline__ float selu_f(float x){
  const float alpha = 1.6732632423543772f;
  const float lam   = 1.0507009873554805f;
  return x > 0.f ? lam * x : lam * alpha * (expf(x) - 1.f);
}
__device__ __forceinline__ float dot4(float4 a, float4 b){
  return a.x * b.x + a.y * b.y + a.z * b.z + a.w * b.w;
}

// ---------------- utility ----------------
__global__ void zero_i32(int* p, int n){
  int i = blockIdx.x * 256 + threadIdx.x;
  if (i < n) p[i] = 0;
}

// ---------------- CSR build ----------------
__global__ void deg_kernel(const int* __restrict__ dst, int* __restrict__ deg, int E){
  int e = blockIdx.x * 256 + threadIdx.x;
  if (e < E) atomicAdd(&deg[dst[e]], 1);
}

__global__ void scan1(const int* __restrict__ deg, int* __restrict__ rp, int* __restrict__ bs, int n){
  __shared__ int sh[256];
  int t = threadIdx.x;
  int base = blockIdx.x * 1024;
  int v[4]; int s = 0;
  #pragma unroll
  for (int i = 0; i < 4; i++){
    int idx = base + t * 4 + i;
    v[i] = (idx < n) ? deg[idx] : 0;
    s += v[i];
  }
  sh[t] = s; __syncthreads();
  for (int off = 1; off < 256; off <<= 1){
    int x = (t >= off) ? sh[t - off] : 0;
    __syncthreads();
    sh[t] += x;
    __syncthreads();
  }
  int run = (t == 0) ? 0 : sh[t - 1];
  #pragma unroll
  for (int i = 0; i < 4; i++){
    int idx = base + t * 4 + i;
    if (idx < n) rp[idx] = run;
    run += v[i];
  }
  if (t == 255) bs[blockIdx.x] = sh[255];
}

__global__ void scan2(int* bs, int nb){
  __shared__ int sh[256];
  int t = threadIdx.x;
  sh[t] = (t < nb) ? bs[t] : 0; __syncthreads();
  for (int off = 1; off < 256; off <<= 1){
    int x = (t >= off) ? sh[t - off] : 0;
    __syncthreads();
    sh[t] += x;
    __syncthreads();
  }
  int excl = (t == 0) ? 0 : sh[t - 1];
  if (t < nb) bs[t] = excl;
}

__global__ void scan3(int* rp, const int* __restrict__ bs, int n, int total){
  int i = blockIdx.x * 256 + threadIdx.x;
  if (i < n) rp[i] += bs[i >> 10];
  if (i == 0) rp[n] = total;
}

__global__ void fill_csr(const int* __restrict__ src, const int* __restrict__ dst,
                         const int* __restrict__ rp, int* __restrict__ fil,
                         int* __restrict__ csr, int E){
  int e = blockIdx.x * 256 + threadIdx.x;
  if (e < E){
    int d = dst[e];
    int p = atomicAdd(&fil[d], 1);
    csr[rp[d] + p] = src[e];
  }
}

// ---------------- weight transposes: Wt[k][m] = W[m][k] ----------------
__global__ void wt_kernel(const float* __restrict__ W1, const float* __restrict__ W2,
                          float* __restrict__ W1t, float* __restrict__ W2t){
  int i = blockIdx.x * 256 + threadIdx.x;
  if (i < 32768){
    int k = i >> 8, m = i & 255;
    W1t[i] = W1[(size_t)m * 128 + k];
  } else if (i < 32768 + 65536){
    int j = i - 32768;
    int k = j >> 8, m = j & 255;
    W2t[j] = W2[(size_t)m * 256 + k];
  }
}

// ---------------- V = attn^T W precompute ----------------
__global__ void compute_v(const float* __restrict__ W1, const float* __restrict__ al1, const float* __restrict__ ar1,
                          const float* __restrict__ W2, const float* __restrict__ al2, const float* __restrict__ ar2,
                          const float* __restrict__ W3, const float* __restrict__ al3, const float* __restrict__ ar3,
                          float* __restrict__ V1L, float* __restrict__ V1R,
                          float* __restrict__ V2L, float* __restrict__ V2R,
                          float* __restrict__ V3L, float* __restrict__ V3R){
  int i = blockIdx.x * 256 + threadIdx.x;
  if (i < 512){
    int h = i >> 7, k = i & 127;
    float sl = 0.f, sr = 0.f;
    for (int dd = 0; dd < 64; dd++){
      float w = W1[(size_t)(h * 64 + dd) * 128 + k];
      sl += al1[h * 64 + dd] * w;
      sr += ar1[h * 64 + dd] * w;
    }
    V1L[i] = sl; V1R[i] = sr;
  } else if (i < 1536){
    int j = i - 512;
    int h = j >> 8, k = j & 255;
    float sl = 0.f, sr = 0.f;
    for (int dd = 0; dd < 64; dd++){
      float w = W2[(size_t)(h * 64 + dd) * 256 + k];
      sl += al2[h * 64 + dd] * w;
      sr += ar2[h * 64 + dd] * w;
    }
    V2L[j] = sl; V2R[j] = sr;
  } else if (i < 1792){
    int k = i - 1536;
    float sl = 0.f, sr = 0.f;
    for (int dd = 0; dd < 64; dd++){
      float w = W3[(size_t)dd * 256 + k];
      sl += al3[dd] * w;
      sr += ar3[dd] * w;
    }
    V3L[k] = sl; V3R[k] = sr;
  }
}

// ---------------- el/er for layer 1 ----------------
__global__ __launch_bounds__(256) void el_er1(const float* __restrict__ x0,
                                              const float* __restrict__ V1L, const float* __restrict__ V1R,
                                              float* __restrict__ el1, float* __restrict__ er1, int n){
  __shared__ float vl[512], vr[512];
  int t = threadIdx.x;
  for (int i = t; i < 512; i += 256){ vl[i] = V1L[i]; vr[i] = V1R[i]; }
  __syncthreads();
  int node = blockIdx.x * 4 + (t >> 6);
  int l = t & 63;
  if (node >= n) return;
  float xa = x0[(size_t)node * 128 + l];
  float xb = x0[(size_t)node * 128 + 64 + l];
  #pragma unroll
  for (int h = 0; h < 4; h++){
    float pl = xa * vl[h * 128 + l] + xb * vl[h * 128 + 64 + l];
    float pr = xa * vr[h * 128 + l] + xb * vr[h * 128 + 64 + l];
    #pragma unroll
    for (int off = 32; off; off >>= 1){ pl += __shfl_xor(pl, off); pr += __shfl_xor(pr, off); }
    if (l == 0){ el1[(size_t)node * 4 + h] = pl; er1[(size_t)node * 4 + h] = pr; }
  }
}

// ---------------- alpha kernels ----------------
__global__ __launch_bounds__(256) void alpha_h4(const float* __restrict__ el, const float* __restrict__ er,
                                                const int* __restrict__ rp, const int* __restrict__ csr,
                                                float* __restrict__ a, int n){
  int node = blockIdx.x * 256 + threadIdx.x;
  if (node >= n) return;
  int s0 = rp[node], s1 = rp[node + 1];
  if (s0 >= s1) return;
  float4 erv = *reinterpret_cast<const float4*>(er + (size_t)node * 4);
  float m0 = -1e30f, m1 = -1e30f, m2 = -1e30f, m3 = -1e30f;
  for (int i = s0; i < s1; i++){
    float4 e = *reinterpret_cast<const float4*>(el + (size_t)csr[i] * 4);
    float e0 = e.x + erv.x; e0 = e0 > 0.f ? e0 : 0.2f * e0; m0 = fmaxf(m0, e0);
    float e1 = e.y + erv.y; e1 = e1 > 0.f ? e1 : 0.2f * e1; m1 = fmaxf(m1, e1);
    float e2 = e.z + erv.z; e2 = e2 > 0.f ? e2 : 0.2f * e2; m2 = fmaxf(m2, e2);
    float e3 = e.w + erv.w; e3 = e3 > 0.f ? e3 : 0.2f * e3; m3 = fmaxf(m3, e3);
  }
  float d0 = 0.f, d1 = 0.f, d2 = 0.f, d3 = 0.f;
  for (int i = s0; i < s1; i++){
    float4 e = *reinterpret_cast<const float4*>(el + (size_t)csr[i] * 4);
    float e0 = e.x + erv.x; e0 = e0 > 0.f ? e0 : 0.2f * e0; d0 += expf(e0 - m0);
    float e1 = e.y + erv.y; e1 = e1 > 0.f ? e1 : 0.2f * e1; d1 += expf(e1 - m1);
    float e2 = e.z + erv.z; e2 = e2 > 0.f ? e2 : 0.2f * e2; d2 += expf(e2 - m2);
    float e3 = e.w + erv.w; e3 = e3 > 0.f ? e3 : 0.2f * e3; d3 += expf(e3 - m3);
  }
  d0 = 1.f / d0; d1 = 1.f / d1; d2 = 1.f / d2; d3 = 1.f / d3;
  for (int i = s0; i < s1; i++){
    float4 e = *reinterpret_cast<const float4*>(el + (size_t)csr[i] * 4);
    float4 o;
    float e0 = e.x + erv.x; e0 = e0 > 0.f ? e0 : 0.2f * e0; o.x = expf(e0 - m0) * d0;
    float e1 = e.y + erv.y; e1 = e1 > 0.f ? e1 : 0.2f * e1; o.y = expf(e1 - m1) * d1;
    float e2 = e.z + erv.z; e2 = e2 > 0.f ? e2 : 0.2f * e2; o.z = expf(e2 - m2) * d2;
    float e3 = e.w + erv.w; e3 = e3 > 0.f ? e3 : 0.2f * e3; o.w = expf(e3 - m3) * d3;
    *reinterpret_cast<float4*>(a + (size_t)i * 4) = o;
  }
}

__global__ __launch_bounds__(256) void alpha_h1(const float* __restrict__ el, const float* __restrict__ er,
                                                const int* __restrict__ rp, const int* __restrict__ csr,
                                                float* __restrict__ a, int n){
  int node = blockIdx.x * 256 + threadIdx.x;
  if (node >= n) return;
  int s0 = rp[node], s1 = rp[node + 1];
  if (s0 >= s1) return;
  float erv = er[node];
  float m = -1e30f;
  for (int i = s0; i < s1; i++){
    float e = el[csr[i]] + erv; e = e > 0.f ? e : 0.2f * e; m = fmaxf(m, e);
  }
  float den = 0.f;
  for (int i = s0; i < s1; i++){
    float e = el[csr[i]] + erv; e = e > 0.f ? e : 0.2f * e; den += expf(e - m);
  }
  float inv = 1.f / den;
  for (int i = s0; i < s1; i++){
    float e = el[csr[i]] + erv; e = e > 0.f ? e : 0.2f * e; a[i] = expf(e - m) * inv;
  }
}

// ---- FUSED layer 1: gather x0 -> GEMM1 -> x1 tile -> el2/er2 + GEMM2 -> y1 = W2*x1 (24b rounded) ----
__global__ __launch_bounds__(512, 4) void l1_fused(
    const float* __restrict__ x0, const float* __restrict__ W1t, const float* __restrict__ bias1,
    const float* __restrict__ a1, const float* __restrict__ W2t,
    const float* __restrict__ V2L, const float* __restrict__ V2R,
    const int* __restrict__ rp, const int* __restrict__ csr,
    ushort_t* __restrict__ y1hi, unsigned char* __restrict__ y1lo,
    float* __restrict__ el2, float* __restrict__ er2){
  __shared__ float aggT[4][B1][132];    // [h][d][k]  33792 B
  __shared__ int rpc[B1 + 1];
  float* x1s = &aggT[0][0][0];          // overlay [16][260] after GEMM1
  int t = threadIdx.x;
  int nb0 = blockIdx.x * B1;
  if (t <= B1) rpc[t] = rp[nb0 + t];
  __syncthreads();

  // ---- gather: half-wave (32 lanes) per dst, float4 cols, depth-2 pipelined ----
  {
    int g = t >> 5, c4 = t & 31;
    int i0 = rpc[g], i1 = rpc[g + 1];
    float acc[4][4] = {{0.f}};
    int s = (i0 < i1) ? csr[i0] : 0;
    for (int i = i0; i < i1; i++){
      int sn = (i + 1 < i1) ? csr[i + 1] : 0;
      float4 av = *reinterpret_cast<const float4*>(a1 + (size_t)i * 4);
      float4 xv = *reinterpret_cast<const float4*>(x0 + (size_t)s * 128 + c4 * 4);
      acc[0][0] += av.x * xv.x; acc[0][1] += av.x * xv.y; acc[0][2] += av.x * xv.z; acc[0][3] += av.x * xv.w;
      acc[1][0] += av.y * xv.x; acc[1][1] += av.y * xv.y; acc[1][2] += av.y * xv.z; acc[1][3] += av.y * xv.w;
      acc[2][0] += av.z * xv.x; acc[2][1] += av.z * xv.y; acc[2][2] += av.z * xv.z; acc[2][3] += av.z * xv.w;
      acc[3][0] += av.w * xv.x; acc[3][1] += av.w * xv.y; acc[3][2] += av.w * xv.z; acc[3][3] += av.w * xv.w;
      s = sn;
    }
    #pragma unroll
    for (int h = 0; h < 4; h++){
      float4 v = make_float4(acc[h][0], acc[h][1], acc[h][2], acc[h][3]);
      *reinterpret_cast<float4*>(&aggT[h][g][c4 * 4]) = v;
    }
  }
  __syncthreads();

  // thread mapping for GEMMs: mq = t>>3 (0..63), dg = t&7 (0..7)
  int mq = t >> 3, dg = t & 7;
  int m0 = mq * 4;
  int hh = mq >> 4;                     // uniform per wave

  // ---- GEMM1: 4m x 2d per thread; W1t rows coalesced across lanes ----
  float acc1[4][2];
  {
    #pragma unroll
    for (int j = 0; j < 4; j++){ acc1[j][0] = 0.f; acc1[j][1] = 0.f; }
    #pragma unroll 2
    for (int kq = 0; kq < 32; kq++){
      int k = kq * 4;
      float4 w0 = *reinterpret_cast<const float4*>(W1t + (size_t)(k + 0) * 256 + m0);
      float4 w1 = *reinterpret_cast<const float4*>(W1t + (size_t)(k + 1) * 256 + m0);
      float4 w2 = *reinterpret_cast<const float4*>(W1t + (size_t)(k + 2) * 256 + m0);
      float4 w3 = *reinterpret_cast<const float4*>(W1t + (size_t)(k + 3) * 256 + m0);
      float4 a0 = *reinterpret_cast<const float4*>(&aggT[hh][dg][k]);
      float4 a1v = *reinterpret_cast<const float4*>(&aggT[hh][dg + 8][k]);
      acc1[0][0] += w0.x * a0.x + w1.x * a0.y + w2.x * a0.z + w3.x * a0.w;
      acc1[1][0] += w0.y * a0.x + w1.y * a0.y + w2.y * a0.z + w3.y * a0.w;
      acc1[2][0] += w0.z * a0.x + w1.z * a0.y + w2.z * a0.z + w3.z * a0.w;
      acc1[3][0] += w0.w * a0.x + w1.w * a0.y + w2.w * a0.z + w3.w * a0.w;
      acc1[0][1] += w0.x * a1v.x + w1.x * a1v.y + w2.x * a1v.z + w3.x * a1v.w;
      acc1[1][1] += w0.y * a1v.x + w1.y * a1v.y + w2.y * a1v.z + w3.y * a1v.w;
      acc1[2][1] += w0.z * a1v.x + w1.z * a1v.y + w2.z * a1v.z + w3.z * a1v.w;
      acc1[3][1] += w0.w * a1v.x + w1.w * a1v.y + w2.w * a1v.z + w3.w * a1v.w;
    }
  }
  __syncthreads();                      // aggT reads done -> overlay x1s
  {
    float4 b = *reinterpret_cast<const float4*>(bias1 + m0);
    #pragma unroll
    for (int r = 0; r < 2; r++){
      int d = dg + 8 * r;
      float4 v;
      v.x = selu_f(acc1[0][r] + b.x);
      v.y = selu_f(acc1[1][r] + b.y);
      v.z = selu_f(acc1[2][r] + b.z);
      v.w = selu_f(acc1[3][r] + b.w);
      *reinterpret_cast<float4*>(&x1s[d * 260 + m0]) = v;
    }
  }
  __syncthreads();

  // ---- GEMM2: y1[d][m] = sum_k W2[m][k]*x1[d][k]; W2t rows coalesced ----
  {
    float acc2[4][2];
    #pragma unroll
    for (int j = 0; j < 4; j++){ acc2[j][0] = 0.f; acc2[j][1] = 0.f; }
    #pragma unroll 2
    for (int kq = 0; kq < 64; kq++){
      int k = kq * 4;
      float4 w0 = *reinterpret_cast<const float4*>(W2t + (size_t)(k + 0) * 256 + m0);
      float4 w1 = *reinterpret_cast<const float4*>(W2t + (size_t)(k + 1) * 256 + m0);
      float4 w2 = *reinterpret_cast<const float4*>(W2t + (size_t)(k + 2) * 256 + m0);
      float4 w3 = *reinterpret_cast<const float4*>(W2t + (size_t)(k + 3) * 256 + m0);
      float4 x0v = *reinterpret_cast<const float4*>(&x1s[dg * 260 + k]);
      float4 x1v = *reinterpret_cast<const float4*>(&x1s[(dg + 8) * 260 + k]);
      acc2[0][0] += w0.x * x0v.x + w1.x * x0v.y + w2.x * x0v.z + w3.x * x0v.w;
      acc2[1][0] += w0.y * x0v.x + w1.y * x0v.y + w2.y * x0v.z + w3.y * x0v.w;
      acc2[2][0] += w0.z * x0v.x + w1.z * x0v.y + w2.z * x0v.z + w3.z * x0v.w;
      acc2[3][0] += w0.w * x0v.x + w1.w * x0v.y + w2.w * x0v.z + w3.w * x0v.w;
      acc2[0][1] += w0.x * x1v.x + w1.x * x1v.y + w2.x * x1v.z + w3.x * x1v.w;
      acc2[1][1] += w0.y * x1v.x + w1.y * x1v.y + w2.y * x1v.z + w3.y * x1v.w;
      acc2[2][1] += w0.z * x1v.x + w1.z * x1v.y + w2.z * x1v.z + w3.z * x1v.w;
      acc2[3][1] += w0.w * x1v.x + w1.w * x1v.y + w2.w * x1v.z + w3.w * x1v.w;
    }
    #pragma unroll
    for (int r = 0; r < 2; r++){
      int d = dg + 8 * r;
      unsigned int u0 = __float_as_uint(acc2[0][r]) + 0x80u;
      unsigned int u1 = __float_as_uint(acc2[1][r]) + 0x80u;
      unsigned int u2 = __float_as_uint(acc2[2][r]) + 0x80u;
      unsigned int u3 = __float_as_uint(acc2[3][r]) + 0x80u;
      ushort4 h4; uchar4 l4;
      h4.x = (ushort_t)(u0 >> 16); h4.y = (ushort_t)(u1 >> 16);
      h4.z = (ushort_t)(u2 >> 16); h4.w = (ushort_t)(u3 >> 16);
      l4.x = (unsigned char)(u0 >> 8); l4.y = (unsigned char)(u1 >> 8);
      l4.z = (unsigned char)(u2 >> 8); l4.w = (unsigned char)(u3 >> 8);
      size_t base = (size_t)(nb0 + d) * 256 + m0;
      *reinterpret_cast<ushort4*>(y1hi + base) = h4;
      *reinterpret_cast<uchar4*>(y1lo + base) = l4;
    }
  }

  // ---- el2/er2 from fp32 x1 tile ----
  if (t < 128){
    int d = t & 15, hq = (t >> 4) & 3, lr = t >> 6;
    const float* V = lr ? V2R : V2L;
    const float4* Vq = reinterpret_cast<const float4*>(V + hq * 256);
    const float4* Xq = reinterpret_cast<const float4*>(&x1s[d * 260]);
    float p = 0.f;
    #pragma unroll 4
    for (int q = 0; q < 64; q++){
      float4 v = Vq[q]; float4 x = Xq[q];
      p += v.x * x.x; p += v.y * x.y; p += v.z * x.z; p += v.w * x.w;
    }
    if (lr) er2[(size_t)(nb0 + d) * 4 + hq] = p;
    else    el2[(size_t)(nb0 + d) * 4 + hq] = p;
  }
}

// ---- layer-2 gather: x2 = selu(sum a2*y1 + b2) -> el3/er3 + feat3 = W3*x2 ----
__global__ __launch_bounds__(256, 4) void l2_gather(
    const ushort_t* __restrict__ y1hi, const unsigned char* __restrict__ y1lo,
    const float* __restrict__ bias2, const float* __restrict__ a2,
    const float* __restrict__ W3,
    const float* __restrict__ V3L, const float* __restrict__ V3R,
    const int* __restrict__ rp, const int* __restrict__ csr,
    float* __restrict__ feat3, float* __restrict__ el3, float* __restrict__ er3){
  __shared__ float x2s[B2G][257];       // 16448 B
  __shared__ float W3c[16 * 257];       // 16448 B
  __shared__ float als[EC2][4];
  __shared__ int   ssrc[EC2];
  __shared__ int   rpc[B2G + 1];
  int t = threadIdx.x;
  int nb0 = blockIdx.x * B2G;
  if (t <= B2G) rpc[t] = rp[nb0 + t];
  __syncthreads();
  int e0 = rpc[0], eN = rpc[B2G];
  int c = t;                            // column 0..255
  int h = c >> 6;

  float acc[B2G];
  #pragma unroll
  for (int d = 0; d < B2G; d++) acc[d] = 0.f;

  for (int c0 = e0; c0 < eN; c0 += EC2){
    int ce = min(EC2, eN - c0);
    for (int i = t; i < ce; i += 256){
      ssrc[i] = csr[c0 + i];
      float4 av = *reinterpret_cast<const float4*>(a2 + (size_t)(c0 + i) * 4);
      als[i][0] = av.x; als[i][1] = av.y; als[i][2] = av.z; als[i][3] = av.w;
    }
    __syncthreads();
    #pragma unroll
    for (int d = 0; d < B2G; d++){
      int lo = max(rpc[d], c0) - c0;
      int hi = min(rpc[d + 1], c0 + ce) - c0;
      for (int i = lo; i < hi; i++){
        size_t s = (size_t)ssrc[i] * 256 + c;
        unsigned int u = ((unsigned int)y1hi[s] << 16) | ((unsigned int)y1lo[s] << 8);
        acc[d] += als[i][h] * __uint_as_float(u);
      }
    }
    __syncthreads();
  }
  {
    float b = bias2[c];
    #pragma unroll
    for (int d = 0; d < B2G; d++) x2s[d][c] = selu_f(acc[d] + b);
  }
  __syncthreads();

  // el3/er3: 32 tasks x 8 threads, interleaved k
  {
    int task = t >> 3, j = t & 7;
    int d = task & 15, lr = task >> 4;
    const float* V = lr ? V3R : V3L;
    float p = 0.f;
    for (int kk = 0; kk < 32; kk++){
      int k = j + kk * 8;
      p += V[k] * x2s[d][k];
    }
    p += __shfl_xor(p, 1); p += __shfl_xor(p, 2); p += __shfl_xor(p, 4);
    if (j == 0){ if (lr) er3[nb0 + d] = p; else el3[nb0 + d] = p; }
  }

  // feat3 = W3 . x2 : 4 chunks of 16 rows staged in LDS
  for (int ch = 0; ch < 4; ch++){
    __syncthreads();
    for (int i = t; i < 16 * 64; i += 256){
      int r = i >> 6, k4 = i & 63;
      float4 w = *reinterpret_cast<const float4*>(W3 + (size_t)(ch * 16 + r) * 256 + k4 * 4);
      W3c[r * 257 + k4 * 4 + 0] = w.x; W3c[r * 257 + k4 * 4 + 1] = w.y;
      W3c[r * 257 + k4 * 4 + 2] = w.z; W3c[r * 257 + k4 * 4 + 3] = w.w;
    }
    __syncthreads();
    {
      int r = t & 15, d = t >> 4;
      float s = 0.f;
      #pragma unroll 4
      for (int k = 0; k < 256; k++) s += W3c[r * 257 + k] * x2s[d][k];
      feat3[(size_t)(nb0 + d) * 64 + ch * 16 + r] = s;
    }
  }
}

// ---------------- layer-3 aggregation, 4-edge batched ----------------
__global__ __launch_bounds__(256) void gat_agg3(const float* __restrict__ feat, const float* __restrict__ a3,
                                                const int* __restrict__ rp, const int* __restrict__ csr,
                                                const float* __restrict__ bias,
                                                float* __restrict__ out, int n){
  int node = blockIdx.x * 4 + (threadIdx.x >> 6);
  int t = threadIdx.x & 63;
  if (node >= n) return;
  int s0 = rp[node], s1 = rp[node + 1];
  float acc = 0.f;
  for (int i = s0; i < s1; i += 4){
    float a[4], f[4];
    #pragma unroll
    for (int j = 0; j < 4; j++){
      int idx = i + j;
      bool vld = idx < s1;
      int idc = vld ? idx : s1 - 1;
      float av = a3[idc];
      if (!vld) av = 0.f;
      a[j] = av;
      f[j] = feat[(size_t)csr[idc] * 64 + t];
    }
    acc += a[0] * f[0] + a[1] * f[1] + a[2] * f[2] + a[3] * f[3];
  }
  out[(size_t)node * 64 + t] = selu_f(acc + bias[t]);
}

// ---------------- readout ----------------
__global__ void readout_kernel(const float* __restrict__ x3, const float* __restrict__ score_w,
                               const float* __restrict__ score_b, const int* __restrict__ gids,
                               float* __restrict__ num, float* __restrict__ den, int n){
  int node = blockIdx.x * 4 + (threadIdx.x >> 6);
  int lane = threadIdx.x & 63;
  if (node >= n) return;
  float xv = x3[(size_t)node * 64 + lane];
  float p = xv * score_w[lane];
  #pragma unroll
  for (int off = 32; off; off >>= 1) p += __shfl_xor(p, off);
  float w = 1.f / (1.f + expf(-(p + score_b[0])));
  int g = gids[node];
  atomicAdd(&num[(size_t)g * 64 + lane], w * xv);
  if (lane == 0) atomicAdd(&den[g], w);
}

// ---------------- final MLP ----------------
__global__ __launch_bounds__(128) void mlp_kernel(
    const float* __restrict__ num, const float* __restrict__ den,
    const float* __restrict__ fg,
    const float* __restrict__ w1, const float* __restrict__ b1,
    const float* __restrict__ w2, const float* __restrict__ b2,
    const float* __restrict__ w3, const float* __restrict__ b3,
    float* __restrict__ out, int G){
  __shared__ float z[80];
  __shared__ float h1[128];
  __shared__ float h2[64];
  int t = threadIdx.x;
  for (int g = blockIdx.x; g < G; g += gridDim.x){
    if (t < 64){
      float d = den[g];
      d = (d == 0.f) ? 1.f : d;
      z[t] = num[(size_t)g * 64 + t] / d;
    } else if (t < 80){
      z[t] = fg[(size_t)g * 16 + (t - 64)];
    }
    __syncthreads();
    {
      float a = b1[t];
      for (int k = 0; k < 80; k++) a += z[k] * w1[t * 80 + k];
      h1[t] = selu_f(a);
    }
    __syncthreads();
    if (t < 64){
      float a = b2[t];
      for (int k = 0; k < 128; k++) a += h1[k] * w2[t * 128 + k];
      h2[t] = selu_f(a);
    }
    __syncthreads();
    if (t < 64){
      float p = h2[t] * w3[t];
      #pragma unroll
      for (int off = 32; off; off >>= 1) p += __shfl_down(p, off);
      if (t == 0) out[g] = p + b3[0];
    }
    __syncthreads();
  }
}

// ---------------- launch ----------------
extern "C" void kernel_launch(void* const* d_in, const int* in_sizes, int n_in,
                              void* d_out, int out_size, void* d_ws, size_t ws_size,
                              hipStream_t stream) {
  const float* feats_node  = (const float*)d_in[0];
  const float* feats_graph = (const float*)d_in[1];
  const int*   src         = (const int*)d_in[2];
  const int*   dst         = (const int*)d_in[3];
  const int*   gids        = (const int*)d_in[4];
  const float* fc1_w   = (const float*)d_in[5];
  const float* attn_l1 = (const float*)d_in[6];
  const float* attn_r1 = (const float*)d_in[7];
  const float* bias1   = (const float*)d_in[8];
  const float* fc2_w   = (const float*)d_in[9];
  const float* attn_l2 = (const float*)d_in[10];
  const float* attn_r2 = (const float*)d_in[11];
  const float* bias2   = (const float*)d_in[12];
  const float* fc3_w   = (const float*)d_in[13];
  const float* attn_l3 = (const float*)d_in[14];
  const float* attn_r3 = (const float*)d_in[15];
  const float* bias3   = (const float*)d_in[16];
  const float* score_w = (const float*)d_in[17];
  const float* score_b = (const float*)d_in[18];
  const float* mlp_w1  = (const float*)d_in[19];
  const float* mlp_b1  = (const float*)d_in[20];
  const float* mlp_w2  = (const float*)d_in[21];
  const float* mlp_b2  = (const float*)d_in[22];
  const float* mlp_w3  = (const float*)d_in[23];
  const float* mlp_b3  = (const float*)d_in[24];
  float* out = (float*)d_out;

  char* ws = (char*)d_ws;
  size_t off = 0;
  auto alloc = [&](size_t bytes) -> void* {
    void* p = ws + off;
    off += (bytes + 255) / 256 * 256;
    return p;
  };
  int*   deg   = (int*)alloc((size_t)N_NODES * 4);
  int*   fil   = (int*)alloc((size_t)N_NODES * 4);
  int*   rp    = (int*)alloc((size_t)(N_NODES + 1) * 4);
  int*   bs    = (int*)alloc(256 * 4);
  int*   csr   = (int*)alloc((size_t)N_EDGES * 4);
  float* elbuf = (float*)alloc((size_t)N_NODES * 4 * 4);
  float* erbuf = (float*)alloc((size_t)N_NODES * 4 * 4);
  float* V1L   = (float*)alloc(512 * 4);
  float* V1R   = (float*)alloc(512 * 4);
  float* V2L   = (float*)alloc(1024 * 4);
  float* V2R   = (float*)alloc(1024 * 4);
  float* V3L   = (float*)alloc(256 * 4);
  float* V3R   = (float*)alloc(256 * 4);
  float* W1t   = (float*)alloc(32768 * 4);
  float* W2t   = (float*)alloc(65536 * 4);
  float* num   = (float*)alloc((size_t)N_GRAPHS * 64 * 4);
  float* den   = (float*)alloc((size_t)N_GRAPHS * 4);
  float* A     = (float*)alloc((size_t)N_EDGES * 4 * 4);
  float* feat3 = (float*)alloc((size_t)N_NODES * 64 * 4);
  ushort_t*      y1hi = (ushort_t*)alloc((size_t)N_NODES * 256 * 2);
  unsigned char* y1lo = (unsigned char*)alloc((size_t)N_NODES * 256);
  float* x3 = (float*)y1hi;  // overlay: y1 dead after l2_gather

  zero_i32<<<(N_NODES + 255) / 256, 256, 0, stream>>>(deg, N_NODES);
  zero_i32<<<(N_NODES + 255) / 256, 256, 0, stream>>>(fil, N_NODES);
  zero_i32<<<(N_GRAPHS * 64 + 255) / 256, 256, 0, stream>>>((int*)num, N_GRAPHS * 64);
  zero_i32<<<(N_GRAPHS + 255) / 256, 256, 0, stream>>>((int*)den, N_GRAPHS);

  deg_kernel<<<(N_EDGES + 255) / 256, 256, 0, stream>>>(dst, deg, N_EDGES);
  scan1<<<196, 256, 0, stream>>>(deg, rp, bs, N_NODES);
  scan2<<<1, 256, 0, stream>>>(bs, 196);
  scan3<<<(N_NODES + 255) / 256, 256, 0, stream>>>(rp, bs, N_NODES, N_EDGES);
  fill_csr<<<(N_EDGES + 255) / 256, 256, 0, stream>>>(src, dst, rp, fil, csr, N_EDGES);

  compute_v<<<7, 256, 0, stream>>>(fc1_w, attn_l1, attn_r1, fc2_w, attn_l2, attn_r2,
                                   fc3_w, attn_l3, attn_r3, V1L, V1R, V2L, V2R, V3L, V3R);
  wt_kernel<<<384, 256, 0, stream>>>(fc1_w, fc2_w, W1t, W2t);
  el_er1<<<N_NODES / 4, 256, 0, stream>>>(feats_node, V1L, V1R, elbuf, erbuf, N_NODES);

  // layer 1 (+ hoisted W2 projection)
  alpha_h4<<<(N_NODES + 255) / 256, 256, 0, stream>>>(elbuf, erbuf, rp, csr, A, N_NODES);
  l1_fused<<<N_NODES / B1, 512, 0, stream>>>(feats_node, W1t, bias1, A, W2t,
                                             V2L, V2R, rp, csr, y1hi, y1lo, elbuf, erbuf);
  // layer 2 (pure gather of y1)
  alpha_h4<<<(N_NODES + 255) / 256, 256, 0, stream>>>(elbuf, erbuf, rp, csr, A, N_NODES);
  l2_gather<<<N_NODES / B2G, 256, 0, stream>>>(y1hi, y1lo, bias2, A, fc3_w,
                                               V3L, V3R, rp, csr, feat3, elbuf, erbuf);
  // layer 3
  alpha_h1<<<(N_NODES + 255) / 256, 256, 0, stream>>>(elbuf, erbuf, rp, csr, A, N_NODES);
  gat_agg3<<<N_NODES / 4, 256, 0, stream>>>(feat3, A, rp, csr, bias3, x3, N_NODES);

  readout_kernel<<<N_NODES / 4, 256, 0, stream>>>(x3, score_w, score_b, gids, num, den, N_NODES);
  mlp_kernel<<<256, 128, 0, stream>>>(num, den, feats_graph,
                                      mlp_w1, mlp_b1, mlp_w2, mlp_b2, mlp_w3, mlp_b3,
                                      out, N_GRAPHS);
}

// Round 16
// 2384.220 us; speedup vs baseline: 1.3850x; 1.0086x over previous
//
#include <hip/hip_runtime.h>
#include <math.h>

#define N_NODES 200000
#define N_EDGES 800000
#define N_GRAPHS 8192
#define B1 16       // dst nodes per block, layer-1 fused
#define B2G 16      // dst nodes per block, layer-2 gather
#define EC2 128

typedef unsigned short ushort_t;

__device__ __forceinline__ float selu_f(float x){
  const float alpha = 1.6732632423543772f;
  const float lam   = 1.0507009873554805f;
  return x > 0.f ? lam * x : lam * alpha * (expf(x) - 1.f);
}
__device__ __forceinline__ float dot4(float4 a, float4 b){
  return a.x * b.x + a.y * b.y + a.z * b.z + a.w * b.w;
}

// ---------------- utility ----------------
__global__ void zero_i32(int* p, int n){
  int i = blockIdx.x * 256 + threadIdx.x;
  if (i < n) p[i] = 0;
}

// ---------------- CSR build ----------------
__global__ void deg_kernel(const int* __restrict__ dst, int* __restrict__ deg, int E){
  int e = blockIdx.x * 256 + threadIdx.x;
  if (e < E) atomicAdd(&deg[dst[e]], 1);
}

__global__ void scan1(const int* __restrict__ deg, int* __restrict__ rp, int* __restrict__ bs, int n){
  __shared__ int sh[256];
  int t = threadIdx.x;
  int base = blockIdx.x * 1024;
  int v[4]; int s = 0;
  #pragma unroll
  for (int i = 0; i < 4; i++){
    int idx = base + t * 4 + i;
    v[i] = (idx < n) ? deg[idx] : 0;
    s += v[i];
  }
  sh[t] = s; __syncthreads();
  for (int off = 1; off < 256; off <<= 1){
    int x = (t >= off) ? sh[t - off] : 0;
    __syncthreads();
    sh[t] += x;
    __syncthreads();
  }
  int run = (t == 0) ? 0 : sh[t - 1];
  #pragma unroll
  for (int i = 0; i < 4; i++){
    int idx = base + t * 4 + i;
    if (idx < n) rp[idx] = run;
    run += v[i];
  }
  if (t == 255) bs[blockIdx.x] = sh[255];
}

__global__ void scan2(int* bs, int nb){
  __shared__ int sh[256];
  int t = threadIdx.x;
  sh[t] = (t < nb) ? bs[t] : 0; __syncthreads();
  for (int off = 1; off < 256; off <<= 1){
    int x = (t >= off) ? sh[t - off] : 0;
    __syncthreads();
    sh[t] += x;
    __syncthreads();
  }
  int excl = (t == 0) ? 0 : sh[t - 1];
  if (t < nb) bs[t] = excl;
}

__global__ void scan3(int* rp, const int* __restrict__ bs, int n, int total){
  int i = blockIdx.x * 256 + threadIdx.x;
  if (i < n) rp[i] += bs[i >> 10];
  if (i == 0) rp[n] = total;
}

__global__ void fill_csr(const int* __restrict__ src, const int* __restrict__ dst,
                         const int* __restrict__ rp, int* __restrict__ fil,
                         int* __restrict__ csr, int E){
  int e = blockIdx.x * 256 + threadIdx.x;
  if (e < E){
    int d = dst[e];
    int p = atomicAdd(&fil[d], 1);
    csr[rp[d] + p] = src[e];
  }
}

// ---------------- weight transposes: Wt[k][m] = W[m][k] ----------------
__global__ void wt_kernel(const float* __restrict__ W1, const float* __restrict__ W2,
                          float* __restrict__ W1t, float* __restrict__ W2t){
  int i = blockIdx.x * 256 + threadIdx.x;
  if (i < 32768){
    int k = i >> 8, m = i & 255;
    W1t[i] = W1[(size_t)m * 128 + k];
  } else if (i < 32768 + 65536){
    int j = i - 32768;
    int k = j >> 8, m = j & 255;
    W2t[j] = W2[(size_t)m * 256 + k];
  }
}

// ---------------- V = attn^T W precompute ----------------
__global__ void compute_v(const float* __restrict__ W1, const float* __restrict__ al1, const float* __restrict__ ar1,
                          const float* __restrict__ W2, const float* __restrict__ al2, const float* __restrict__ ar2,
                          const float* __restrict__ W3, const float* __restrict__ al3, const float* __restrict__ ar3,
                          float* __restrict__ V1L, float* __restrict__ V1R,
                          float* __restrict__ V2L, float* __restrict__ V2R,
                          float* __restrict__ V3L, float* __restrict__ V3R){
  int i = blockIdx.x * 256 + threadIdx.x;
  if (i < 512){
    int h = i >> 7, k = i & 127;
    float sl = 0.f, sr = 0.f;
    for (int dd = 0; dd < 64; dd++){
      float w = W1[(size_t)(h * 64 + dd) * 128 + k];
      sl += al1[h * 64 + dd] * w;
      sr += ar1[h * 64 + dd] * w;
    }
    V1L[i] = sl; V1R[i] = sr;
  } else if (i < 1536){
    int j = i - 512;
    int h = j >> 8, k = j & 255;
    float sl = 0.f, sr = 0.f;
    for (int dd = 0; dd < 64; dd++){
      float w = W2[(size_t)(h * 64 + dd) * 256 + k];
      sl += al2[h * 64 + dd] * w;
      sr += ar2[h * 64 + dd] * w;
    }
    V2L[j] = sl; V2R[j] = sr;
  } else if (i < 1792){
    int k = i - 1536;
    float sl = 0.f, sr = 0.f;
    for (int dd = 0; dd < 64; dd++){
      float w = W3[(size_t)dd * 256 + k];
      sl += al3[dd] * w;
      sr += ar3[dd] * w;
    }
    V3L[k] = sl; V3R[k] = sr;
  }
}

// ---------------- el/er for layer 1 ----------------
__global__ __launch_bounds__(256) void el_er1(const float* __restrict__ x0,
                                              const float* __restrict__ V1L, const float* __restrict__ V1R,
                                              float* __restrict__ el1, float* __restrict__ er1, int n){
  __shared__ float vl[512], vr[512];
  int t = threadIdx.x;
  for (int i = t; i < 512; i += 256){ vl[i] = V1L[i]; vr[i] = V1R[i]; }
  __syncthreads();
  int node = blockIdx.x * 4 + (t >> 6);
  int l = t & 63;
  if (node >= n) return;
  float xa = x0[(size_t)node * 128 + l];
  float xb = x0[(size_t)node * 128 + 64 + l];
  #pragma unroll
  for (int h = 0; h < 4; h++){
    float pl = xa * vl[h * 128 + l] + xb * vl[h * 128 + 64 + l];
    float pr = xa * vr[h * 128 + l] + xb * vr[h * 128 + 64 + l];
    #pragma unroll
    for (int off = 32; off; off >>= 1){ pl += __shfl_xor(pl, off); pr += __shfl_xor(pr, off); }
    if (l == 0){ el1[(size_t)node * 4 + h] = pl; er1[(size_t)node * 4 + h] = pr; }
  }
}

// ---------------- alpha kernels ----------------
__global__ __launch_bounds__(256) void alpha_h4(const float* __restrict__ el, const float* __restrict__ er,
                                                const int* __restrict__ rp, const int* __restrict__ csr,
                                                float* __restrict__ a, int n){
  int node = blockIdx.x * 256 + threadIdx.x;
  if (node >= n) return;
  int s0 = rp[node], s1 = rp[node + 1];
  if (s0 >= s1) return;
  float4 erv = *reinterpret_cast<const float4*>(er + (size_t)node * 4);
  float m0 = -1e30f, m1 = -1e30f, m2 = -1e30f, m3 = -1e30f;
  for (int i = s0; i < s1; i++){
    float4 e = *reinterpret_cast<const float4*>(el + (size_t)csr[i] * 4);
    float e0 = e.x + erv.x; e0 = e0 > 0.f ? e0 : 0.2f * e0; m0 = fmaxf(m0, e0);
    float e1 = e.y + erv.y; e1 = e1 > 0.f ? e1 : 0.2f * e1; m1 = fmaxf(m1, e1);
    float e2 = e.z + erv.z; e2 = e2 > 0.f ? e2 : 0.2f * e2; m2 = fmaxf(m2, e2);
    float e3 = e.w + erv.w; e3 = e3 > 0.f ? e3 : 0.2f * e3; m3 = fmaxf(m3, e3);
  }
  float d0 = 0.f, d1 = 0.f, d2 = 0.f, d3 = 0.f;
  for (int i = s0; i < s1; i++){
    float4 e = *reinterpret_cast<const float4*>(el + (size_t)csr[i] * 4);
    float e0 = e.x + erv.x; e0 = e0 > 0.f ? e0 : 0.2f * e0; d0 += expf(e0 - m0);
    float e1 = e.y + erv.y; e1 = e1 > 0.f ? e1 : 0.2f * e1; d1 += expf(e1 - m1);
    float e2 = e.z + erv.z; e2 = e2 > 0.f ? e2 : 0.2f * e2; d2 += expf(e2 - m2);
    float e3 = e.w + erv.w; e3 = e3 > 0.f ? e3 : 0.2f * e3; d3 += expf(e3 - m3);
  }
  d0 = 1.f / d0; d1 = 1.f / d1; d2 = 1.f / d2; d3 = 1.f / d3;
  for (int i = s0; i < s1; i++){
    float4 e = *reinterpret_cast<const float4*>(el + (size_t)csr[i] * 4);
    float4 o;
    float e0 = e.x + erv.x; e0 = e0 > 0.f ? e0 : 0.2f * e0; o.x = expf(e0 - m0) * d0;
    float e1 = e.y + erv.y; e1 = e1 > 0.f ? e1 : 0.2f * e1; o.y = expf(e1 - m1) * d1;
    float e2 = e.z + erv.z; e2 = e2 > 0.f ? e2 : 0.2f * e2; o.z = expf(e2 - m2) * d2;
    float e3 = e.w + erv.w; e3 = e3 > 0.f ? e3 : 0.2f * e3; o.w = expf(e3 - m3) * d3;
    *reinterpret_cast<float4*>(a + (size_t)i * 4) = o;
  }
}

__global__ __launch_bounds__(256) void alpha_h1(const float* __restrict__ el, const float* __restrict__ er,
                                                const int* __restrict__ rp, const int* __restrict__ csr,
                                                float* __restrict__ a, int n){
  int node = blockIdx.x * 256 + threadIdx.x;
  if (node >= n) return;
  int s0 = rp[node], s1 = rp[node + 1];
  if (s0 >= s1) return;
  float erv = er[node];
  float m = -1e30f;
  for (int i = s0; i < s1; i++){
    float e = el[csr[i]] + erv; e = e > 0.f ? e : 0.2f * e; m = fmaxf(m, e);
  }
  float den = 0.f;
  for (int i = s0; i < s1; i++){
    float e = el[csr[i]] + erv; e = e > 0.f ? e : 0.2f * e; den += expf(e - m);
  }
  float inv = 1.f / den;
  for (int i = s0; i < s1; i++){
    float e = el[csr[i]] + erv; e = e > 0.f ? e : 0.2f * e; a[i] = expf(e - m) * inv;
  }
}

// ---- FUSED layer 1: gather x0 -> GEMM1 -> x1 tile -> el2/er2 + GEMM2 -> y1 = W2*x1 (24b rounded) ----
// GEMM thread map: wave w owns m-cols [32w,32w+32) for ALL dsts -> W fetched once per block.
__global__ __launch_bounds__(512, 4) void l1_fused(
    const float* __restrict__ x0, const float* __restrict__ W1t, const float* __restrict__ bias1,
    const float* __restrict__ a1, const float* __restrict__ W2t,
    const float* __restrict__ V2L, const float* __restrict__ V2R,
    const int* __restrict__ rp, const int* __restrict__ csr,
    ushort_t* __restrict__ y1hi, unsigned char* __restrict__ y1lo,
    float* __restrict__ el2, float* __restrict__ er2){
  __shared__ float aggT[4][B1][132];    // [h][d][k]  33792 B
  __shared__ int rpc[B1 + 1];
  float* x1s = &aggT[0][0][0];          // overlay [16][260] after GEMM1
  int t = threadIdx.x;
  int nb0 = blockIdx.x * B1;
  if (t <= B1) rpc[t] = rp[nb0 + t];
  __syncthreads();

  // ---- gather: half-wave (32 lanes) per dst, float4 cols, depth-2 pipelined ----
  {
    int g = t >> 5, c4 = t & 31;
    int i0 = rpc[g], i1 = rpc[g + 1];
    float acc[4][4] = {{0.f}};
    int s = (i0 < i1) ? csr[i0] : 0;
    for (int i = i0; i < i1; i++){
      int sn = (i + 1 < i1) ? csr[i + 1] : 0;
      float4 av = *reinterpret_cast<const float4*>(a1 + (size_t)i * 4);
      float4 xv = *reinterpret_cast<const float4*>(x0 + (size_t)s * 128 + c4 * 4);
      acc[0][0] += av.x * xv.x; acc[0][1] += av.x * xv.y; acc[0][2] += av.x * xv.z; acc[0][3] += av.x * xv.w;
      acc[1][0] += av.y * xv.x; acc[1][1] += av.y * xv.y; acc[1][2] += av.y * xv.z; acc[1][3] += av.y * xv.w;
      acc[2][0] += av.z * xv.x; acc[2][1] += av.z * xv.y; acc[2][2] += av.z * xv.z; acc[2][3] += av.z * xv.w;
      acc[3][0] += av.w * xv.x; acc[3][1] += av.w * xv.y; acc[3][2] += av.w * xv.z; acc[3][3] += av.w * xv.w;
      s = sn;
    }
    #pragma unroll
    for (int h = 0; h < 4; h++){
      float4 v = make_float4(acc[h][0], acc[h][1], acc[h][2], acc[h][3]);
      *reinterpret_cast<float4*>(&aggT[h][g][c4 * 4]) = v;
    }
  }
  __syncthreads();

  // thread mapping: wave wv owns m-slice; lanes 0..7 = m, lanes /8 = d-group
  int wv = t >> 6, ln = t & 63;
  int mq = wv * 8 + (ln & 7);           // 0..63
  int dg = ln >> 3;                     // 0..7
  int m0 = mq * 4;
  int hh = mq >> 4;                     // uniform per wave

  // ---- GEMM1: 4m x 2d per thread; wave-sliced W1t (fetched once per block) ----
  float acc1[4][2];
  {
    #pragma unroll
    for (int j = 0; j < 4; j++){ acc1[j][0] = 0.f; acc1[j][1] = 0.f; }
    #pragma unroll 2
    for (int kq = 0; kq < 32; kq++){
      int k = kq * 4;
      float4 w0 = *reinterpret_cast<const float4*>(W1t + (size_t)(k + 0) * 256 + m0);
      float4 w1 = *reinterpret_cast<const float4*>(W1t + (size_t)(k + 1) * 256 + m0);
      float4 w2 = *reinterpret_cast<const float4*>(W1t + (size_t)(k + 2) * 256 + m0);
      float4 w3 = *reinterpret_cast<const float4*>(W1t + (size_t)(k + 3) * 256 + m0);
      float4 a0 = *reinterpret_cast<const float4*>(&aggT[hh][dg][k]);
      float4 a1v = *reinterpret_cast<const float4*>(&aggT[hh][dg + 8][k]);
      acc1[0][0] += w0.x * a0.x + w1.x * a0.y + w2.x * a0.z + w3.x * a0.w;
      acc1[1][0] += w0.y * a0.x + w1.y * a0.y + w2.y * a0.z + w3.y * a0.w;
      acc1[2][0] += w0.z * a0.x + w1.z * a0.y + w2.z * a0.z + w3.z * a0.w;
      acc1[3][0] += w0.w * a0.x + w1.w * a0.y + w2.w * a0.z + w3.w * a0.w;
      acc1[0][1] += w0.x * a1v.x + w1.x * a1v.y + w2.x * a1v.z + w3.x * a1v.w;
      acc1[1][1] += w0.y * a1v.x + w1.y * a1v.y + w2.y * a1v.z + w3.y * a1v.w;
      acc1[2][1] += w0.z * a1v.x + w1.z * a1v.y + w2.z * a1v.z + w3.z * a1v.w;
      acc1[3][1] += w0.w * a1v.x + w1.w * a1v.y + w2.w * a1v.z + w3.w * a1v.w;
    }
  }
  __syncthreads();                      // aggT reads done -> overlay x1s
  {
    float4 b = *reinterpret_cast<const float4*>(bias1 + m0);
    #pragma unroll
    for (int r = 0; r < 2; r++){
      int d = dg + 8 * r;
      float4 v;
      v.x = selu_f(acc1[0][r] + b.x);
      v.y = selu_f(acc1[1][r] + b.y);
      v.z = selu_f(acc1[2][r] + b.z);
      v.w = selu_f(acc1[3][r] + b.w);
      *reinterpret_cast<float4*>(&x1s[d * 260 + m0]) = v;
    }
  }
  __syncthreads();

  // ---- GEMM2: y1[d][m] = sum_k W2[m][k]*x1[d][k]; wave-sliced W2t ----
  {
    float acc2[4][2];
    #pragma unroll
    for (int j = 0; j < 4; j++){ acc2[j][0] = 0.f; acc2[j][1] = 0.f; }
    #pragma unroll 2
    for (int kq = 0; kq < 64; kq++){
      int k = kq * 4;
      float4 w0 = *reinterpret_cast<const float4*>(W2t + (size_t)(k + 0) * 256 + m0);
      float4 w1 = *reinterpret_cast<const float4*>(W2t + (size_t)(k + 1) * 256 + m0);
      float4 w2 = *reinterpret_cast<const float4*>(W2t + (size_t)(k + 2) * 256 + m0);
      float4 w3 = *reinterpret_cast<const float4*>(W2t + (size_t)(k + 3) * 256 + m0);
      float4 x0v = *reinterpret_cast<const float4*>(&x1s[dg * 260 + k]);
      float4 x1v = *reinterpret_cast<const float4*>(&x1s[(dg + 8) * 260 + k]);
      acc2[0][0] += w0.x * x0v.x + w1.x * x0v.y + w2.x * x0v.z + w3.x * x0v.w;
      acc2[1][0] += w0.y * x0v.x + w1.y * x0v.y + w2.y * x0v.z + w3.y * x0v.w;
      acc2[2][0] += w0.z * x0v.x + w1.z * x0v.y + w2.z * x0v.z + w3.z * x0v.w;
      acc2[3][0] += w0.w * x0v.x + w1.w * x0v.y + w2.w * x0v.z + w3.w * x0v.w;
      acc2[0][1] += w0.x * x1v.x + w1.x * x1v.y + w2.x * x1v.z + w3.x * x1v.w;
      acc2[1][1] += w0.y * x1v.x + w1.y * x1v.y + w2.y * x1v.z + w3.y * x1v.w;
      acc2[2][1] += w0.z * x1v.x + w1.z * x1v.y + w2.z * x1v.z + w3.z * x1v.w;
      acc2[3][1] += w0.w * x1v.x + w1.w * x1v.y + w2.w * x1v.z + w3.w * x1v.w;
    }
    #pragma unroll
    for (int r = 0; r < 2; r++){
      int d = dg + 8 * r;
      unsigned int u0 = __float_as_uint(acc2[0][r]) + 0x80u;
      unsigned int u1 = __float_as_uint(acc2[1][r]) + 0x80u;
      unsigned int u2 = __float_as_uint(acc2[2][r]) + 0x80u;
      unsigned int u3 = __float_as_uint(acc2[3][r]) + 0x80u;
      ushort4 h4; uchar4 l4;
      h4.x = (ushort_t)(u0 >> 16); h4.y = (ushort_t)(u1 >> 16);
      h4.z = (ushort_t)(u2 >> 16); h4.w = (ushort_t)(u3 >> 16);
      l4.x = (unsigned char)(u0 >> 8); l4.y = (unsigned char)(u1 >> 8);
      l4.z = (unsigned char)(u2 >> 8); l4.w = (unsigned char)(u3 >> 8);
      size_t base = (size_t)(nb0 + d) * 256 + m0;
      *reinterpret_cast<ushort4*>(y1hi + base) = h4;
      *reinterpret_cast<uchar4*>(y1lo + base) = l4;
    }
  }

  // ---- el2/er2 from fp32 x1 tile ----
  if (t < 128){
    int d = t & 15, hq = (t >> 4) & 3, lr = t >> 6;
    const float* V = lr ? V2R : V2L;
    const float4* Vq = reinterpret_cast<const float4*>(V + hq * 256);
    const float4* Xq = reinterpret_cast<const float4*>(&x1s[d * 260]);
    float p = 0.f;
    #pragma unroll 4
    for (int q = 0; q < 64; q++){
      float4 v = Vq[q]; float4 x = Xq[q];
      p += v.x * x.x; p += v.y * x.y; p += v.z * x.z; p += v.w * x.w;
    }
    if (lr) er2[(size_t)(nb0 + d) * 4 + hq] = p;
    else    el2[(size_t)(nb0 + d) * 4 + hq] = p;
  }
}

// ---- layer-2 gather: x2 = selu(sum a2*y1 + b2) -> el3/er3 + feat3 = W3*x2 ----
__global__ __launch_bounds__(256, 4) void l2_gather(
    const ushort_t* __restrict__ y1hi, const unsigned char* __restrict__ y1lo,
    const float* __restrict__ bias2, const float* __restrict__ a2,
    const float* __restrict__ W3,
    const float* __restrict__ V3L, const float* __restrict__ V3R,
    const int* __restrict__ rp, const int* __restrict__ csr,
    float* __restrict__ feat3, float* __restrict__ el3, float* __restrict__ er3){
  __shared__ float x2s[B2G][257];       // 16448 B
  __shared__ float W3c[16 * 257];       // 16448 B
  __shared__ float als[EC2][4];
  __shared__ int   ssrc[EC2];
  __shared__ int   rpc[B2G + 1];
  int t = threadIdx.x;
  int nb0 = blockIdx.x * B2G;
  if (t <= B2G) rpc[t] = rp[nb0 + t];
  __syncthreads();
  int e0 = rpc[0], eN = rpc[B2G];
  int c = t;                            // column 0..255
  int h = c >> 6;

  float acc[B2G];
  #pragma unroll
  for (int d = 0; d < B2G; d++) acc[d] = 0.f;

  for (int c0 = e0; c0 < eN; c0 += EC2){
    int ce = min(EC2, eN - c0);
    for (int i = t; i < ce; i += 256){
      ssrc[i] = csr[c0 + i];
      float4 av = *reinterpret_cast<const float4*>(a2 + (size_t)(c0 + i) * 4);
      als[i][0] = av.x; als[i][1] = av.y; als[i][2] = av.z; als[i][3] = av.w;
    }
    __syncthreads();
    #pragma unroll
    for (int d = 0; d < B2G; d++){
      int lo = max(rpc[d], c0) - c0;
      int hi = min(rpc[d + 1], c0 + ce) - c0;
      for (int i = lo; i < hi; i++){
        size_t s = (size_t)ssrc[i] * 256 + c;
        unsigned int u = ((unsigned int)y1hi[s] << 16) | ((unsigned int)y1lo[s] << 8);
        acc[d] += als[i][h] * __uint_as_float(u);
      }
    }
    __syncthreads();
  }
  {
    float b = bias2[c];
    #pragma unroll
    for (int d = 0; d < B2G; d++) x2s[d][c] = selu_f(acc[d] + b);
  }
  __syncthreads();

  // el3/er3: 32 tasks x 8 threads, interleaved k
  {
    int task = t >> 3, j = t & 7;
    int d = task & 15, lr = task >> 4;
    const float* V = lr ? V3R : V3L;
    float p = 0.f;
    for (int kk = 0; kk < 32; kk++){
      int k = j + kk * 8;
      p += V[k] * x2s[d][k];
    }
    p += __shfl_xor(p, 1); p += __shfl_xor(p, 2); p += __shfl_xor(p, 4);
    if (j == 0){ if (lr) er3[nb0 + d] = p; else el3[nb0 + d] = p; }
  }

  // feat3 = W3 . x2 : 4 chunks of 16 rows staged in LDS
  for (int ch = 0; ch < 4; ch++){
    __syncthreads();
    for (int i = t; i < 16 * 64; i += 256){
      int r = i >> 6, k4 = i & 63;
      float4 w = *reinterpret_cast<const float4*>(W3 + (size_t)(ch * 16 + r) * 256 + k4 * 4);
      W3c[r * 257 + k4 * 4 + 0] = w.x; W3c[r * 257 + k4 * 4 + 1] = w.y;
      W3c[r * 257 + k4 * 4 + 2] = w.z; W3c[r * 257 + k4 * 4 + 3] = w.w;
    }
    __syncthreads();
    {
      int r = t & 15, d = t >> 4;
      float s = 0.f;
      #pragma unroll 4
      for (int k = 0; k < 256; k++) s += W3c[r * 257 + k] * x2s[d][k];
      feat3[(size_t)(nb0 + d) * 64 + ch * 16 + r] = s;
    }
  }
}

// ---------------- layer-3 aggregation, 4-edge batched ----------------
__global__ __launch_bounds__(256) void gat_agg3(const float* __restrict__ feat, const float* __restrict__ a3,
                                                const int* __restrict__ rp, const int* __restrict__ csr,
                                                const float* __restrict__ bias,
                                                float* __restrict__ out, int n){
  int node = blockIdx.x * 4 + (threadIdx.x >> 6);
  int t = threadIdx.x & 63;
  if (node >= n) return;
  int s0 = rp[node], s1 = rp[node + 1];
  float acc = 0.f;
  for (int i = s0; i < s1; i += 4){
    float a[4], f[4];
    #pragma unroll
    for (int j = 0; j < 4; j++){
      int idx = i + j;
      bool vld = idx < s1;
      int idc = vld ? idx : s1 - 1;
      float av = a3[idc];
      if (!vld) av = 0.f;
      a[j] = av;
      f[j] = feat[(size_t)csr[idc] * 64 + t];
    }
    acc += a[0] * f[0] + a[1] * f[1] + a[2] * f[2] + a[3] * f[3];
  }
  out[(size_t)node * 64 + t] = selu_f(acc + bias[t]);
}

// ---------------- readout ----------------
__global__ void readout_kernel(const float* __restrict__ x3, const float* __restrict__ score_w,
                               const float* __restrict__ score_b, const int* __restrict__ gids,
                               float* __restrict__ num, float* __restrict__ den, int n){
  int node = blockIdx.x * 4 + (threadIdx.x >> 6);
  int lane = threadIdx.x & 63;
  if (node >= n) return;
  float xv = x3[(size_t)node * 64 + lane];
  float p = xv * score_w[lane];
  #pragma unroll
  for (int off = 32; off; off >>= 1) p += __shfl_xor(p, off);
  float w = 1.f / (1.f + expf(-(p + score_b[0])));
  int g = gids[node];
  atomicAdd(&num[(size_t)g * 64 + lane], w * xv);
  if (lane == 0) atomicAdd(&den[g], w);
}

// ---------------- final MLP ----------------
__global__ __launch_bounds__(128) void mlp_kernel(
    const float* __restrict__ num, const float* __restrict__ den,
    const float* __restrict__ fg,
    const float* __restrict__ w1, const float* __restrict__ b1,
    const float* __restrict__ w2, const float* __restrict__ b2,
    const float* __restrict__ w3, const float* __restrict__ b3,
    float* __restrict__ out, int G){
  __shared__ float z[80];
  __shared__ float h1[128];
  __shared__ float h2[64];
  int t = threadIdx.x;
  for (int g = blockIdx.x; g < G; g += gridDim.x){
    if (t < 64){
      float d = den[g];
      d = (d == 0.f) ? 1.f : d;
      z[t] = num[(size_t)g * 64 + t] / d;
    } else if (t < 80){
      z[t] = fg[(size_t)g * 16 + (t - 64)];
    }
    __syncthreads();
    {
      float a = b1[t];
      for (int k = 0; k < 80; k++) a += z[k] * w1[t * 80 + k];
      h1[t] = selu_f(a);
    }
    __syncthreads();
    if (t < 64){
      float a = b2[t];
      for (int k = 0; k < 128; k++) a += h1[k] * w2[t * 128 + k];
      h2[t] = selu_f(a);
    }
    __syncthreads();
    if (t < 64){
      float p = h2[t] * w3[t];
      #pragma unroll
      for (int off = 32; off; off >>= 1) p += __shfl_down(p, off);
      if (t == 0) out[g] = p + b3[0];
    }
    __syncthreads();
  }
}

// ---------------- launch ----------------
extern "C" void kernel_launch(void* const* d_in, const int* in_sizes, int n_in,
                              void* d_out, int out_size, void* d_ws, size_t ws_size,
                              hipStream_t stream) {
  const float* feats_node  = (const float*)d_in[0];
  const float* feats_graph = (const float*)d_in[1];
  const int*   src         = (const int*)d_in[2];
  const int*   dst         = (const int*)d_in[3];
  const int*   gids        = (const int*)d_in[4];
  const float* fc1_w   = (const float*)d_in[5];
  const float* attn_l1 = (const float*)d_in[6];
  const float* attn_r1 = (const float*)d_in[7];
  const float* bias1   = (const float*)d_in[8];
  const float* fc2_w   = (const float*)d_in[9];
  const float* attn_l2 = (const float*)d_in[10];
  const float* attn_r2 = (const float*)d_in[11];
  const float* bias2   = (const float*)d_in[12];
  const float* fc3_w   = (const float*)d_in[13];
  const float* attn_l3 = (const float*)d_in[14];
  const float* attn_r3 = (const float*)d_in[15];
  const float* bias3   = (const float*)d_in[16];
  const float* score_w = (const float*)d_in[17];
  const float* score_b = (const float*)d_in[18];
  const float* mlp_w1  = (const float*)d_in[19];
  const float* mlp_b1  = (const float*)d_in[20];
  const float* mlp_w2  = (const float*)d_in[21];
  const float* mlp_b2  = (const float*)d_in[22];
  const float* mlp_w3  = (const float*)d_in[23];
  const float* mlp_b3  = (const float*)d_in[24];
  float* out = (float*)d_out;

  char* ws = (char*)d_ws;
  size_t off = 0;
  auto alloc = [&](size_t bytes) -> void* {
    void* p = ws + off;
    off += (bytes + 255) / 256 * 256;
    return p;
  };
  int*   deg   = (int*)alloc((size_t)N_NODES * 4);
  int*   fil   = (int*)alloc((size_t)N_NODES * 4);
  int*   rp    = (int*)alloc((size_t)(N_NODES + 1) * 4);
  int*   bs    = (int*)alloc(256 * 4);
  int*   csr   = (int*)alloc((size_t)N_EDGES * 4);
  float* elbuf = (float*)alloc((size_t)N_NODES * 4 * 4);
  float* erbuf = (float*)alloc((size_t)N_NODES * 4 * 4);
  float* V1L   = (float*)alloc(512 * 4);
  float* V1R   = (float*)alloc(512 * 4);
  float* V2L   = (float*)alloc(1024 * 4);
  float* V2R   = (float*)alloc(1024 * 4);
  float* V3L   = (float*)alloc(256 * 4);
  float* V3R   = (float*)alloc(256 * 4);
  float* W1t   = (float*)alloc(32768 * 4);
  float* W2t   = (float*)alloc(65536 * 4);
  float* num   = (float*)alloc((size_t)N_GRAPHS * 64 * 4);
  float* den   = (float*)alloc((size_t)N_GRAPHS * 4);
  float* A     = (float*)alloc((size_t)N_EDGES * 4 * 4);
  float* feat3 = (float*)alloc((size_t)N_NODES * 64 * 4);
  ushort_t*      y1hi = (ushort_t*)alloc((size_t)N_NODES * 256 * 2);
  unsigned char* y1lo = (unsigned char*)alloc((size_t)N_NODES * 256);
  float* x3 = (float*)y1hi;  // overlay: y1 dead after l2_gather

  zero_i32<<<(N_NODES + 255) / 256, 256, 0, stream>>>(deg, N_NODES);
  zero_i32<<<(N_NODES + 255) / 256, 256, 0, stream>>>(fil, N_NODES);
  zero_i32<<<(N_GRAPHS * 64 + 255) / 256, 256, 0, stream>>>((int*)num, N_GRAPHS * 64);
  zero_i32<<<(N_GRAPHS + 255) / 256, 256, 0, stream>>>((int*)den, N_GRAPHS);

  deg_kernel<<<(N_EDGES + 255) / 256, 256, 0, stream>>>(dst, deg, N_EDGES);
  scan1<<<196, 256, 0, stream>>>(deg, rp, bs, N_NODES);
  scan2<<<1, 256, 0, stream>>>(bs, 196);
  scan3<<<(N_NODES + 255) / 256, 256, 0, stream>>>(rp, bs, N_NODES, N_EDGES);
  fill_csr<<<(N_EDGES + 255) / 256, 256, 0, stream>>>(src, dst, rp, fil, csr, N_EDGES);

  compute_v<<<7, 256, 0, stream>>>(fc1_w, attn_l1, attn_r1, fc2_w, attn_l2, attn_r2,
                                   fc3_w, attn_l3, attn_r3, V1L, V1R, V2L, V2R, V3L, V3R);
  wt_kernel<<<384, 256, 0, stream>>>(fc1_w, fc2_w, W1t, W2t);
  el_er1<<<N_NODES / 4, 256, 0, stream>>>(feats_node, V1L, V1R, elbuf, erbuf, N_NODES);

  // layer 1 (+ hoisted W2 projection)
  alpha_h4<<<(N_NODES + 255) / 256, 256, 0, stream>>>(elbuf, erbuf, rp, csr, A, N_NODES);
  l1_fused<<<N_NODES / B1, 512, 0, stream>>>(feats_node, W1t, bias1, A, W2t,
                                             V2L, V2R, rp, csr, y1hi, y1lo, elbuf, erbuf);
  // layer 2 (pure gather of y1)
  alpha_h4<<<(N_NODES + 255) / 256, 256, 0, stream>>>(elbuf, erbuf, rp, csr, A, N_NODES);
  l2_gather<<<N_NODES / B2G, 256, 0, stream>>>(y1hi, y1lo, bias2, A, fc3_w,
                                               V3L, V3R, rp, csr, feat3, elbuf, erbuf);
  // layer 3
  alpha_h1<<<(N_NODES + 255) / 256, 256, 0, stream>>>(elbuf, erbuf, rp, csr, A, N_NODES);
  gat_agg3<<<N_NODES / 4, 256, 0, stream>>>(feat3, A, rp, csr, bias3, x3, N_NODES);

  readout_kernel<<<N_NODES / 4, 256, 0, stream>>>(x3, score_w, score_b, gids, num, den, N_NODES);
  mlp_kernel<<<256, 128, 0, stream>>>(num, den, feats_graph,
                                      mlp_w1, mlp_b1, mlp_w2, mlp_b2, mlp_w3, mlp_b3,
                                      out, N_GRAPHS);
}

// Round 17
// 2273.923 us; speedup vs baseline: 1.4522x; 1.0485x over previous
//
#include <hip/hip_runtime.h>
#include <math.h>

#define N_NODES 200000
#define N_EDGES 800000
#define N_GRAPHS 8192
#define B1 16       // dst nodes per block, layer-1 fused
#define B2G 16      // dst nodes per block, layer-2 gather
#define EC2 128

typedef unsigned short ushort_t;

__device__ __forceinline__ float selu_f(float x){
  const float alpha = 1.6732632423543772f;
  const float lam   = 1.0507009873554805f;
  return x > 0.f ? lam * x : lam * alpha * (expf(x) - 1.f);
}

// ---------------- utility ----------------
__global__ void zero_i32(int* p, int n){
  int i = blockIdx.x * 256 + threadIdx.x;
  if (i < n) p[i] = 0;
}

// ---------------- CSR build ----------------
__global__ void deg_kernel(const int* __restrict__ dst, int* __restrict__ deg, int E){
  int e = blockIdx.x * 256 + threadIdx.x;
  if (e < E) atomicAdd(&deg[dst[e]], 1);
}

__global__ void scan1(const int* __restrict__ deg, int* __restrict__ rp, int* __restrict__ bs, int n){
  __shared__ int sh[256];
  int t = threadIdx.x;
  int base = blockIdx.x * 1024;
  int v[4]; int s = 0;
  #pragma unroll
  for (int i = 0; i < 4; i++){
    int idx = base + t * 4 + i;
    v[i] = (idx < n) ? deg[idx] : 0;
    s += v[i];
  }
  sh[t] = s; __syncthreads();
  for (int off = 1; off < 256; off <<= 1){
    int x = (t >= off) ? sh[t - off] : 0;
    __syncthreads();
    sh[t] += x;
    __syncthreads();
  }
  int run = (t == 0) ? 0 : sh[t - 1];
  #pragma unroll
  for (int i = 0; i < 4; i++){
    int idx = base + t * 4 + i;
    if (idx < n) rp[idx] = run;
    run += v[i];
  }
  if (t == 255) bs[blockIdx.x] = sh[255];
}

__global__ void scan2(int* bs, int nb){
  __shared__ int sh[256];
  int t = threadIdx.x;
  sh[t] = (t < nb) ? bs[t] : 0; __syncthreads();
  for (int off = 1; off < 256; off <<= 1){
    int x = (t >= off) ? sh[t - off] : 0;
    __syncthreads();
    sh[t] += x;
    __syncthreads();
  }
  int excl = (t == 0) ? 0 : sh[t - 1];
  if (t < nb) bs[t] = excl;
}

__global__ void scan3(int* rp, const int* __restrict__ bs, int n, int total){
  int i = blockIdx.x * 256 + threadIdx.x;
  if (i < n) rp[i] += bs[i >> 10];
  if (i == 0) rp[n] = total;
}

__global__ void fill_csr(const int* __restrict__ src, const int* __restrict__ dst,
                         const int* __restrict__ rp, int* __restrict__ fil,
                         int* __restrict__ csr, int E){
  int e = blockIdx.x * 256 + threadIdx.x;
  if (e < E){
    int d = dst[e];
    int p = atomicAdd(&fil[d], 1);
    csr[rp[d] + p] = src[e];
  }
}

// ---------------- weight transposes: Wt[k][m] = W[m][k] ----------------
__global__ void wt_kernel(const float* __restrict__ W1, const float* __restrict__ W2,
                          float* __restrict__ W1t, float* __restrict__ W2t){
  int i = blockIdx.x * 256 + threadIdx.x;
  if (i < 32768){
    int k = i >> 8, m = i & 255;
    W1t[i] = W1[(size_t)m * 128 + k];
  } else if (i < 32768 + 65536){
    int j = i - 32768;
    int k = j >> 8, m = j & 255;
    W2t[j] = W2[(size_t)m * 256 + k];
  }
}

// ---------------- V = attn^T W precompute ----------------
__global__ void compute_v(const float* __restrict__ W1, const float* __restrict__ al1, const float* __restrict__ ar1,
                          const float* __restrict__ W2, const float* __restrict__ al2, const float* __restrict__ ar2,
                          const float* __restrict__ W3, const float* __restrict__ al3, const float* __restrict__ ar3,
                          float* __restrict__ V1L, float* __restrict__ V1R,
                          float* __restrict__ V2L, float* __restrict__ V2R,
                          float* __restrict__ V3L, float* __restrict__ V3R){
  int i = blockIdx.x * 256 + threadIdx.x;
  if (i < 512){
    int h = i >> 7, k = i & 127;
    float sl = 0.f, sr = 0.f;
    for (int dd = 0; dd < 64; dd++){
      float w = W1[(size_t)(h * 64 + dd) * 128 + k];
      sl += al1[h * 64 + dd] * w;
      sr += ar1[h * 64 + dd] * w;
    }
    V1L[i] = sl; V1R[i] = sr;
  } else if (i < 1536){
    int j = i - 512;
    int h = j >> 8, k = j & 255;
    float sl = 0.f, sr = 0.f;
    for (int dd = 0; dd < 64; dd++){
      float w = W2[(size_t)(h * 64 + dd) * 256 + k];
      sl += al2[h * 64 + dd] * w;
      sr += ar2[h * 64 + dd] * w;
    }
    V2L[j] = sl; V2R[j] = sr;
  } else if (i < 1792){
    int k = i - 1536;
    float sl = 0.f, sr = 0.f;
    for (int dd = 0; dd < 64; dd++){
      float w = W3[(size_t)dd * 256 + k];
      sl += al3[dd] * w;
      sr += ar3[dd] * w;
    }
    V3L[k] = sl; V3R[k] = sr;
  }
}

// ---------------- el/er for layer 1 ----------------
__global__ __launch_bounds__(256) void el_er1(const float* __restrict__ x0,
                                              const float* __restrict__ V1L, const float* __restrict__ V1R,
                                              float* __restrict__ el1, float* __restrict__ er1, int n){
  __shared__ float vl[512], vr[512];
  int t = threadIdx.x;
  for (int i = t; i < 512; i += 256){ vl[i] = V1L[i]; vr[i] = V1R[i]; }
  __syncthreads();
  int node = blockIdx.x * 4 + (t >> 6);
  int l = t & 63;
  if (node >= n) return;
  float xa = x0[(size_t)node * 128 + l];
  float xb = x0[(size_t)node * 128 + 64 + l];
  #pragma unroll
  for (int h = 0; h < 4; h++){
    float pl = xa * vl[h * 128 + l] + xb * vl[h * 128 + 64 + l];
    float pr = xa * vr[h * 128 + l] + xb * vr[h * 128 + 64 + l];
    #pragma unroll
    for (int off = 32; off; off >>= 1){ pl += __shfl_xor(pl, off); pr += __shfl_xor(pr, off); }
    if (l == 0){ el1[(size_t)node * 4 + h] = pl; er1[(size_t)node * 4 + h] = pr; }
  }
}

// ---------------- alpha kernels ----------------
__global__ __launch_bounds__(256) void alpha_h4(const float* __restrict__ el, const float* __restrict__ er,
                                                const int* __restrict__ rp, const int* __restrict__ csr,
                                                float* __restrict__ a, int n){
  int node = blockIdx.x * 256 + threadIdx.x;
  if (node >= n) return;
  int s0 = rp[node], s1 = rp[node + 1];
  if (s0 >= s1) return;
  float4 erv = *reinterpret_cast<const float4*>(er + (size_t)node * 4);
  float m0 = -1e30f, m1 = -1e30f, m2 = -1e30f, m3 = -1e30f;
  for (int i = s0; i < s1; i++){
    float4 e = *reinterpret_cast<const float4*>(el + (size_t)csr[i] * 4);
    float e0 = e.x + erv.x; e0 = e0 > 0.f ? e0 : 0.2f * e0; m0 = fmaxf(m0, e0);
    float e1 = e.y + erv.y; e1 = e1 > 0.f ? e1 : 0.2f * e1; m1 = fmaxf(m1, e1);
    float e2 = e.z + erv.z; e2 = e2 > 0.f ? e2 : 0.2f * e2; m2 = fmaxf(m2, e2);
    float e3 = e.w + erv.w; e3 = e3 > 0.f ? e3 : 0.2f * e3; m3 = fmaxf(m3, e3);
  }
  float d0 = 0.f, d1 = 0.f, d2 = 0.f, d3 = 0.f;
  for (int i = s0; i < s1; i++){
    float4 e = *reinterpret_cast<const float4*>(el + (size_t)csr[i] * 4);
    float e0 = e.x + erv.x; e0 = e0 > 0.f ? e0 : 0.2f * e0; d0 += expf(e0 - m0);
    float e1 = e.y + erv.y; e1 = e1 > 0.f ? e1 : 0.2f * e1; d1 += expf(e1 - m1);
    float e2 = e.z + erv.z; e2 = e2 > 0.f ? e2 : 0.2f * e2; d2 += expf(e2 - m2);
    float e3 = e.w + erv.w; e3 = e3 > 0.f ? e3 : 0.2f * e3; d3 += expf(e3 - m3);
  }
  d0 = 1.f / d0; d1 = 1.f / d1; d2 = 1.f / d2; d3 = 1.f / d3;
  for (int i = s0; i < s1; i++){
    float4 e = *reinterpret_cast<const float4*>(el + (size_t)csr[i] * 4);
    float4 o;
    float e0 = e.x + erv.x; e0 = e0 > 0.f ? e0 : 0.2f * e0; o.x = expf(e0 - m0) * d0;
    float e1 = e.y + erv.y; e1 = e1 > 0.f ? e1 : 0.2f * e1; o.y = expf(e1 - m1) * d1;
    float e2 = e.z + erv.z; e2 = e2 > 0.f ? e2 : 0.2f * e2; o.z = expf(e2 - m2) * d2;
    float e3 = e.w + erv.w; e3 = e3 > 0.f ? e3 : 0.2f * e3; o.w = expf(e3 - m3) * d3;
    *reinterpret_cast<float4*>(a + (size_t)i * 4) = o;
  }
}

__global__ __launch_bounds__(256) void alpha_h1(const float* __restrict__ el, const float* __restrict__ er,
                                                const int* __restrict__ rp, const int* __restrict__ csr,
                                                float* __restrict__ a, int n){
  int node = blockIdx.x * 256 + threadIdx.x;
  if (node >= n) return;
  int s0 = rp[node], s1 = rp[node + 1];
  if (s0 >= s1) return;
  float erv = er[node];
  float m = -1e30f;
  for (int i = s0; i < s1; i++){
    float e = el[csr[i]] + erv; e = e > 0.f ? e : 0.2f * e; m = fmaxf(m, e);
  }
  float den = 0.f;
  for (int i = s0; i < s1; i++){
    float e = el[csr[i]] + erv; e = e > 0.f ? e : 0.2f * e; den += expf(e - m);
  }
  float inv = 1.f / den;
  for (int i = s0; i < s1; i++){
    float e = el[csr[i]] + erv; e = e > 0.f ? e : 0.2f * e; a[i] = expf(e - m) * inv;
  }
}

// ---- FUSED layer 1: gather x0 -> GEMM1 -> x1 tile -> el2/er2 + GEMM2 -> y1 = W2*x1 (24b rounded) ----
// GEMM thread map: wave w owns m-cols [32w,32w+32) for ALL dsts -> W fetched once per block.
__global__ __launch_bounds__(512, 4) void l1_fused(
    const float* __restrict__ x0, const float* __restrict__ W1t, const float* __restrict__ bias1,
    const float* __restrict__ a1, const float* __restrict__ W2t,
    const float* __restrict__ V2L, const float* __restrict__ V2R,
    const int* __restrict__ rp, const int* __restrict__ csr,
    ushort_t* __restrict__ y1hi, unsigned char* __restrict__ y1lo,
    float* __restrict__ el2, float* __restrict__ er2){
  __shared__ float aggT[4][B1][132];    // [h][d][k]  33792 B
  __shared__ int rpc[B1 + 1];
  float* x1s = &aggT[0][0][0];          // overlay [16][260] after GEMM1
  int t = threadIdx.x;
  int nb0 = blockIdx.x * B1;
  if (t <= B1) rpc[t] = rp[nb0 + t];
  __syncthreads();

  // ---- gather: half-wave (32 lanes) per dst, float4 cols, 4-edge batched loads ----
  {
    int g = t >> 5, c4 = t & 31;
    int i0 = rpc[g], i1 = rpc[g + 1];
    float acc[4][4] = {{0.f}};
    for (int i = i0; i < i1; i += 4){
      float4 av[4]; float4 xv[4];
      #pragma unroll
      for (int j = 0; j < 4; j++){
        int idx = i + j;
        bool vld = idx < i1;
        int idc = vld ? idx : i1 - 1;
        int s = csr[idc];
        float4 a = *reinterpret_cast<const float4*>(a1 + (size_t)idc * 4);
        if (!vld) a = make_float4(0.f, 0.f, 0.f, 0.f);
        av[j] = a;
        xv[j] = *reinterpret_cast<const float4*>(x0 + (size_t)s * 128 + c4 * 4);
      }
      #pragma unroll
      for (int j = 0; j < 4; j++){
        acc[0][0] += av[j].x * xv[j].x; acc[0][1] += av[j].x * xv[j].y;
        acc[0][2] += av[j].x * xv[j].z; acc[0][3] += av[j].x * xv[j].w;
        acc[1][0] += av[j].y * xv[j].x; acc[1][1] += av[j].y * xv[j].y;
        acc[1][2] += av[j].y * xv[j].z; acc[1][3] += av[j].y * xv[j].w;
        acc[2][0] += av[j].z * xv[j].x; acc[2][1] += av[j].z * xv[j].y;
        acc[2][2] += av[j].z * xv[j].z; acc[2][3] += av[j].z * xv[j].w;
        acc[3][0] += av[j].w * xv[j].x; acc[3][1] += av[j].w * xv[j].y;
        acc[3][2] += av[j].w * xv[j].z; acc[3][3] += av[j].w * xv[j].w;
      }
    }
    #pragma unroll
    for (int h = 0; h < 4; h++){
      float4 v = make_float4(acc[h][0], acc[h][1], acc[h][2], acc[h][3]);
      *reinterpret_cast<float4*>(&aggT[h][g][c4 * 4]) = v;
    }
  }
  __syncthreads();

  // thread mapping: wave wv owns m-slice; lanes 0..7 = m, lanes /8 = d-group
  int wv = t >> 6, ln = t & 63;
  int mq = wv * 8 + (ln & 7);           // 0..63
  int dg = ln >> 3;                     // 0..7
  int m0 = mq * 4;
  int hh = mq >> 4;                     // uniform per wave

  // ---- GEMM1: 4m x 2d per thread; wave-sliced W1t (fetched once per block) ----
  float acc1[4][2];
  {
    #pragma unroll
    for (int j = 0; j < 4; j++){ acc1[j][0] = 0.f; acc1[j][1] = 0.f; }
    #pragma unroll 2
    for (int kq = 0; kq < 32; kq++){
      int k = kq * 4;
      float4 w0 = *reinterpret_cast<const float4*>(W1t + (size_t)(k + 0) * 256 + m0);
      float4 w1 = *reinterpret_cast<const float4*>(W1t + (size_t)(k + 1) * 256 + m0);
      float4 w2 = *reinterpret_cast<const float4*>(W1t + (size_t)(k + 2) * 256 + m0);
      float4 w3 = *reinterpret_cast<const float4*>(W1t + (size_t)(k + 3) * 256 + m0);
      float4 a0 = *reinterpret_cast<const float4*>(&aggT[hh][dg][k]);
      float4 a1v = *reinterpret_cast<const float4*>(&aggT[hh][dg + 8][k]);
      acc1[0][0] += w0.x * a0.x + w1.x * a0.y + w2.x * a0.z + w3.x * a0.w;
      acc1[1][0] += w0.y * a0.x + w1.y * a0.y + w2.y * a0.z + w3.y * a0.w;
      acc1[2][0] += w0.z * a0.x + w1.z * a0.y + w2.z * a0.z + w3.z * a0.w;
      acc1[3][0] += w0.w * a0.x + w1.w * a0.y + w2.w * a0.z + w3.w * a0.w;
      acc1[0][1] += w0.x * a1v.x + w1.x * a1v.y + w2.x * a1v.z + w3.x * a1v.w;
      acc1[1][1] += w0.y * a1v.x + w1.y * a1v.y + w2.y * a1v.z + w3.y * a1v.w;
      acc1[2][1] += w0.z * a1v.x + w1.z * a1v.y + w2.z * a1v.z + w3.z * a1v.w;
      acc1[3][1] += w0.w * a1v.x + w1.w * a1v.y + w2.w * a1v.z + w3.w * a1v.w;
    }
  }
  __syncthreads();                      // aggT reads done -> overlay x1s
  {
    float4 b = *reinterpret_cast<const float4*>(bias1 + m0);
    #pragma unroll
    for (int r = 0; r < 2; r++){
      int d = dg + 8 * r;
      float4 v;
      v.x = selu_f(acc1[0][r] + b.x);
      v.y = selu_f(acc1[1][r] + b.y);
      v.z = selu_f(acc1[2][r] + b.z);
      v.w = selu_f(acc1[3][r] + b.w);
      *reinterpret_cast<float4*>(&x1s[d * 260 + m0]) = v;
    }
  }
  __syncthreads();

  // ---- GEMM2: y1[d][m] = sum_k W2[m][k]*x1[d][k]; wave-sliced W2t ----
  {
    float acc2[4][2];
    #pragma unroll
    for (int j = 0; j < 4; j++){ acc2[j][0] = 0.f; acc2[j][1] = 0.f; }
    #pragma unroll 2
    for (int kq = 0; kq < 64; kq++){
      int k = kq * 4;
      float4 w0 = *reinterpret_cast<const float4*>(W2t + (size_t)(k + 0) * 256 + m0);
      float4 w1 = *reinterpret_cast<const float4*>(W2t + (size_t)(k + 1) * 256 + m0);
      float4 w2 = *reinterpret_cast<const float4*>(W2t + (size_t)(k + 2) * 256 + m0);
      float4 w3 = *reinterpret_cast<const float4*>(W2t + (size_t)(k + 3) * 256 + m0);
      float4 x0v = *reinterpret_cast<const float4*>(&x1s[dg * 260 + k]);
      float4 x1v = *reinterpret_cast<const float4*>(&x1s[(dg + 8) * 260 + k]);
      acc2[0][0] += w0.x * x0v.x + w1.x * x0v.y + w2.x * x0v.z + w3.x * x0v.w;
      acc2[1][0] += w0.y * x0v.x + w1.y * x0v.y + w2.y * x0v.z + w3.y * x0v.w;
      acc2[2][0] += w0.z * x0v.x + w1.z * x0v.y + w2.z * x0v.z + w3.z * x0v.w;
      acc2[3][0] += w0.w * x0v.x + w1.w * x0v.y + w2.w * x0v.z + w3.w * x0v.w;
      acc2[0][1] += w0.x * x1v.x + w1.x * x1v.y + w2.x * x1v.z + w3.x * x1v.w;
      acc2[1][1] += w0.y * x1v.x + w1.y * x1v.y + w2.y * x1v.z + w3.y * x1v.w;
      acc2[2][1] += w0.z * x1v.x + w1.z * x1v.y + w2.z * x1v.z + w3.z * x1v.w;
      acc2[3][1] += w0.w * x1v.x + w1.w * x1v.y + w2.w * x1v.z + w3.w * x1v.w;
    }
    #pragma unroll
    for (int r = 0; r < 2; r++){
      int d = dg + 8 * r;
      unsigned int u0 = __float_as_uint(acc2[0][r]) + 0x80u;
      unsigned int u1 = __float_as_uint(acc2[1][r]) + 0x80u;
      unsigned int u2 = __float_as_uint(acc2[2][r]) + 0x80u;
      unsigned int u3 = __float_as_uint(acc2[3][r]) + 0x80u;
      ushort4 h4; uchar4 l4;
      h4.x = (ushort_t)(u0 >> 16); h4.y = (ushort_t)(u1 >> 16);
      h4.z = (ushort_t)(u2 >> 16); h4.w = (ushort_t)(u3 >> 16);
      l4.x = (unsigned char)(u0 >> 8); l4.y = (unsigned char)(u1 >> 8);
      l4.z = (unsigned char)(u2 >> 8); l4.w = (unsigned char)(u3 >> 8);
      size_t base = (size_t)(nb0 + d) * 256 + m0;
      *reinterpret_cast<ushort4*>(y1hi + base) = h4;
      *reinterpret_cast<uchar4*>(y1lo + base) = l4;
    }
  }

  // ---- el2/er2 from fp32 x1 tile ----
  if (t < 128){
    int d = t & 15, hq = (t >> 4) & 3, lr = t >> 6;
    const float* V = lr ? V2R : V2L;
    const float4* Vq = reinterpret_cast<const float4*>(V + hq * 256);
    const float4* Xq = reinterpret_cast<const float4*>(&x1s[d * 260]);
    float p = 0.f;
    #pragma unroll 4
    for (int q = 0; q < 64; q++){
      float4 v = Vq[q]; float4 x = Xq[q];
      p += v.x * x.x; p += v.y * x.y; p += v.z * x.z; p += v.w * x.w;
    }
    if (lr) er2[(size_t)(nb0 + d) * 4 + hq] = p;
    else    el2[(size_t)(nb0 + d) * 4 + hq] = p;
  }
}

// ---- layer-2 gather: x2 = selu(sum a2*y1 + b2) -> el3/er3 + feat3 = W3*x2 ----
__global__ __launch_bounds__(256, 4) void l2_gather(
    const ushort_t* __restrict__ y1hi, const unsigned char* __restrict__ y1lo,
    const float* __restrict__ bias2, const float* __restrict__ a2,
    const float* __restrict__ W3,
    const float* __restrict__ V3L, const float* __restrict__ V3R,
    const int* __restrict__ rp, const int* __restrict__ csr,
    float* __restrict__ feat3, float* __restrict__ el3, float* __restrict__ er3){
  __shared__ float x2s[B2G][257];       // 16448 B
  __shared__ float W3c[16 * 257];       // 16448 B
  __shared__ float als[EC2][4];
  __shared__ int   ssrc[EC2];
  __shared__ int   rpc[B2G + 1];
  int t = threadIdx.x;
  int nb0 = blockIdx.x * B2G;
  if (t <= B2G) rpc[t] = rp[nb0 + t];
  __syncthreads();
  int e0 = rpc[0], eN = rpc[B2G];
  int c = t;                            // column 0..255
  int h = c >> 6;

  float acc[B2G];
  #pragma unroll
  for (int d = 0; d < B2G; d++) acc[d] = 0.f;

  for (int c0 = e0; c0 < eN; c0 += EC2){
    int ce = min(EC2, eN - c0);
    for (int i = t; i < ce; i += 256){
      ssrc[i] = csr[c0 + i];
      float4 av = *reinterpret_cast<const float4*>(a2 + (size_t)(c0 + i) * 4);
      als[i][0] = av.x; als[i][1] = av.y; als[i][2] = av.z; als[i][3] = av.w;
    }
    __syncthreads();
    #pragma unroll
    for (int d = 0; d < B2G; d++){
      int lo = max(rpc[d], c0) - c0;
      int hi = min(rpc[d + 1], c0 + ce) - c0;
      for (int i = lo; i < hi; i += 4){
        float aj[4]; unsigned int uj[4];
        #pragma unroll
        for (int j = 0; j < 4; j++){
          int idx = i + j;
          bool vld = idx < hi;
          int idc = vld ? idx : hi - 1;
          int s = ssrc[idc];
          aj[j] = vld ? als[idc][h] : 0.f;
          size_t o = (size_t)s * 256 + c;
          uj[j] = ((unsigned int)y1hi[o] << 16) | ((unsigned int)y1lo[o] << 8);
        }
        acc[d] += aj[0] * __uint_as_float(uj[0]) + aj[1] * __uint_as_float(uj[1])
                + aj[2] * __uint_as_float(uj[2]) + aj[3] * __uint_as_float(uj[3]);
      }
    }
    __syncthreads();
  }
  {
    float b = bias2[c];
    #pragma unroll
    for (int d = 0; d < B2G; d++) x2s[d][c] = selu_f(acc[d] + b);
  }
  __syncthreads();

  // el3/er3: 32 tasks x 8 threads, interleaved k
  {
    int task = t >> 3, j = t & 7;
    int d = task & 15, lr = task >> 4;
    const float* V = lr ? V3R : V3L;
    float p = 0.f;
    for (int kk = 0; kk < 32; kk++){
      int k = j + kk * 8;
      p += V[k] * x2s[d][k];
    }
    p += __shfl_xor(p, 1); p += __shfl_xor(p, 2); p += __shfl_xor(p, 4);
    if (j == 0){ if (lr) er3[nb0 + d] = p; else el3[nb0 + d] = p; }
  }

  // feat3 = W3 . x2 : 4 chunks of 16 rows staged in LDS
  for (int ch = 0; ch < 4; ch++){
    __syncthreads();
    for (int i = t; i < 16 * 64; i += 256){
      int r = i >> 6, k4 = i & 63;
      float4 w = *reinterpret_cast<const float4*>(W3 + (size_t)(ch * 16 + r) * 256 + k4 * 4);
      W3c[r * 257 + k4 * 4 + 0] = w.x; W3c[r * 257 + k4 * 4 + 1] = w.y;
      W3c[r * 257 + k4 * 4 + 2] = w.z; W3c[r * 257 + k4 * 4 + 3] = w.w;
    }
    __syncthreads();
    {
      int r = t & 15, d = t >> 4;
      float s = 0.f;
      #pragma unroll 4
      for (int k = 0; k < 256; k++) s += W3c[r * 257 + k] * x2s[d][k];
      feat3[(size_t)(nb0 + d) * 64 + ch * 16 + r] = s;
    }
  }
}

// ---------------- layer-3 aggregation, 4-edge batched ----------------
__global__ __launch_bounds__(256) void gat_agg3(const float* __restrict__ feat, const float* __restrict__ a3,
                                                const int* __restrict__ rp, const int* __restrict__ csr,
                                                const float* __restrict__ bias,
                                                float* __restrict__ out, int n){
  int node = blockIdx.x * 4 + (threadIdx.x >> 6);
  int t = threadIdx.x & 63;
  if (node >= n) return;
  int s0 = rp[node], s1 = rp[node + 1];
  float acc = 0.f;
  for (int i = s0; i < s1; i += 4){
    float a[4], f[4];
    #pragma unroll
    for (int j = 0; j < 4; j++){
      int idx = i + j;
      bool vld = idx < s1;
      int idc = vld ? idx : s1 - 1;
      float av = a3[idc];
      if (!vld) av = 0.f;
      a[j] = av;
      f[j] = feat[(size_t)csr[idc] * 64 + t];
    }
    acc += a[0] * f[0] + a[1] * f[1] + a[2] * f[2] + a[3] * f[3];
  }
  out[(size_t)node * 64 + t] = selu_f(acc + bias[t]);
}

// ---------------- readout ----------------
__global__ void readout_kernel(const float* __restrict__ x3, const float* __restrict__ score_w,
                               const float* __restrict__ score_b, const int* __restrict__ gids,
                               float* __restrict__ num, float* __restrict__ den, int n){
  int node = blockIdx.x * 4 + (threadIdx.x >> 6);
  int lane = threadIdx.x & 63;
  if (node >= n) return;
  float xv = x3[(size_t)node * 64 + lane];
  float p = xv * score_w[lane];
  #pragma unroll
  for (int off = 32; off; off >>= 1) p += __shfl_xor(p, off);
  float w = 1.f / (1.f + expf(-(p + score_b[0])));
  int g = gids[node];
  atomicAdd(&num[(size_t)g * 64 + lane], w * xv);
  if (lane == 0) atomicAdd(&den[g], w);
}

// ---------------- final MLP ----------------
__global__ __launch_bounds__(128) void mlp_kernel(
    const float* __restrict__ num, const float* __restrict__ den,
    const float* __restrict__ fg,
    const float* __restrict__ w1, const float* __restrict__ b1,
    const float* __restrict__ w2, const float* __restrict__ b2,
    const float* __restrict__ w3, const float* __restrict__ b3,
    float* __restrict__ out, int G){
  __shared__ float z[80];
  __shared__ float h1[128];
  __shared__ float h2[64];
  int t = threadIdx.x;
  for (int g = blockIdx.x; g < G; g += gridDim.x){
    if (t < 64){
      float d = den[g];
      d = (d == 0.f) ? 1.f : d;
      z[t] = num[(size_t)g * 64 + t] / d;
    } else if (t < 80){
      z[t] = fg[(size_t)g * 16 + (t - 64)];
    }
    __syncthreads();
    {
      float a = b1[t];
      for (int k = 0; k < 80; k++) a += z[k] * w1[t * 80 + k];
      h1[t] = selu_f(a);
    }
    __syncthreads();
    if (t < 64){
      float a = b2[t];
      for (int k = 0; k < 128; k++) a += h1[k] * w2[t * 128 + k];
      h2[t] = selu_f(a);
    }
    __syncthreads();
    if (t < 64){
      float p = h2[t] * w3[t];
      #pragma unroll
      for (int off = 32; off; off >>= 1) p += __shfl_down(p, off);
      if (t == 0) out[g] = p + b3[0];
    }
    __syncthreads();
  }
}

// ---------------- launch ----------------
extern "C" void kernel_launch(void* const* d_in, const int* in_sizes, int n_in,
                              void* d_out, int out_size, void* d_ws, size_t ws_size,
                              hipStream_t stream) {
  const float* feats_node  = (const float*)d_in[0];
  const float* feats_graph = (const float*)d_in[1];
  const int*   src         = (const int*)d_in[2];
  const int*   dst         = (const int*)d_in[3];
  const int*   gids        = (const int*)d_in[4];
  const float* fc1_w   = (const float*)d_in[5];
  const float* attn_l1 = (const float*)d_in[6];
  const float* attn_r1 = (const float*)d_in[7];
  const float* bias1   = (const float*)d_in[8];
  const float* fc2_w   = (const float*)d_in[9];
  const float* attn_l2 = (const float*)d_in[10];
  const float* attn_r2 = (const float*)d_in[11];
  const float* bias2   = (const float*)d_in[12];
  const float* fc3_w   = (const float*)d_in[13];
  const float* attn_l3 = (const float*)d_in[14];
  const float* attn_r3 = (const float*)d_in[15];
  const float* bias3   = (const float*)d_in[16];
  const float* score_w = (const float*)d_in[17];
  const float* score_b = (const float*)d_in[18];
  const float* mlp_w1  = (const float*)d_in[19];
  const float* mlp_b1  = (const float*)d_in[20];
  const float* mlp_w2  = (const float*)d_in[21];
  const float* mlp_b2  = (const float*)d_in[22];
  const float* mlp_w3  = (const float*)d_in[23];
  const float* mlp_b3  = (const float*)d_in[24];
  float* out = (float*)d_out;

  char* ws = (char*)d_ws;
  size_t off = 0;
  auto alloc = [&](size_t bytes) -> void* {
    void* p = ws + off;
    off += (bytes + 255) / 256 * 256;
    return p;
  };
  int*   deg   = (int*)alloc((size_t)N_NODES * 4);
  int*   fil   = (int*)alloc((size_t)N_NODES * 4);
  int*   rp    = (int*)alloc((size_t)(N_NODES + 1) * 4);
  int*   bs    = (int*)alloc(256 * 4);
  int*   csr   = (int*)alloc((size_t)N_EDGES * 4);
  float* elbuf = (float*)alloc((size_t)N_NODES * 4 * 4);
  float* erbuf = (float*)alloc((size_t)N_NODES * 4 * 4);
  float* V1L   = (float*)alloc(512 * 4);
  float* V1R   = (float*)alloc(512 * 4);
  float* V2L   = (float*)alloc(1024 * 4);
  float* V2R   = (float*)alloc(1024 * 4);
  float* V3L   = (float*)alloc(256 * 4);
  float* V3R   = (float*)alloc(256 * 4);
  float* W1t   = (float*)alloc(32768 * 4);
  float* W2t   = (float*)alloc(65536 * 4);
  float* num   = (float*)alloc((size_t)N_GRAPHS * 64 * 4);
  float* den   = (float*)alloc((size_t)N_GRAPHS * 4);
  float* A     = (float*)alloc((size_t)N_EDGES * 4 * 4);
  float* feat3 = (float*)alloc((size_t)N_NODES * 64 * 4);
  ushort_t*      y1hi = (ushort_t*)alloc((size_t)N_NODES * 256 * 2);
  unsigned char* y1lo = (unsigned char*)alloc((size_t)N_NODES * 256);
  float* x3 = (float*)y1hi;  // overlay: y1 dead after l2_gather

  zero_i32<<<(N_NODES + 255) / 256, 256, 0, stream>>>(deg, N_NODES);
  zero_i32<<<(N_NODES + 255) / 256, 256, 0, stream>>>(fil, N_NODES);
  zero_i32<<<(N_GRAPHS * 64 + 255) / 256, 256, 0, stream>>>((int*)num, N_GRAPHS * 64);
  zero_i32<<<(N_GRAPHS + 255) / 256, 256, 0, stream>>>((int*)den, N_GRAPHS);

  deg_kernel<<<(N_EDGES + 255) / 256, 256, 0, stream>>>(dst, deg, N_EDGES);
  scan1<<<196, 256, 0, stream>>>(deg, rp, bs, N_NODES);
  scan2<<<1, 256, 0, stream>>>(bs, 196);
  scan3<<<(N_NODES + 255) / 256, 256, 0, stream>>>(rp, bs, N_NODES, N_EDGES);
  fill_csr<<<(N_EDGES + 255) / 256, 256, 0, stream>>>(src, dst, rp, fil, csr, N_EDGES);

  compute_v<<<7, 256, 0, stream>>>(fc1_w, attn_l1, attn_r1, fc2_w, attn_l2, attn_r2,
                                   fc3_w, attn_l3, attn_r3, V1L, V1R, V2L, V2R, V3L, V3R);
  wt_kernel<<<384, 256, 0, stream>>>(fc1_w, fc2_w, W1t, W2t);
  el_er1<<<N_NODES / 4, 256, 0, stream>>>(feats_node, V1L, V1R, elbuf, erbuf, N_NODES);

  // layer 1 (+ hoisted W2 projection)
  alpha_h4<<<(N_NODES + 255) / 256, 256, 0, stream>>>(elbuf, erbuf, rp, csr, A, N_NODES);
  l1_fused<<<N_NODES / B1, 512, 0, stream>>>(feats_node, W1t, bias1, A, W2t,
                                             V2L, V2R, rp, csr, y1hi, y1lo, elbuf, erbuf);
  // layer 2 (pure gather of y1)
  alpha_h4<<<(N_NODES + 255) / 256, 256, 0, stream>>>(elbuf, erbuf, rp, csr, A, N_NODES);
  l2_gather<<<N_NODES / B2G, 256, 0, stream>>>(y1hi, y1lo, bias2, A, fc3_w,
                                               V3L, V3R, rp, csr, feat3, elbuf, erbuf);
  // layer 3
  alpha_h1<<<(N_NODES + 255) / 256, 256, 0, stream>>>(elbuf, erbuf, rp, csr, A, N_NODES);
  gat_agg3<<<N_NODES / 4, 256, 0, stream>>>(feat3, A, rp, csr, bias3, x3, N_NODES);

  readout_kernel<<<N_NODES / 4, 256, 0, stream>>>(x3, score_w, score_b, gids, num, den, N_NODES);
  mlp_kernel<<<256, 128, 0, stream>>>(num, den, feats_graph,
                                      mlp_w1, mlp_b1, mlp_w2, mlp_b2, mlp_w3, mlp_b3,
                                      out, N_GRAPHS);
}